// Round 6
// baseline (324.883 us; speedup 1.0000x reference)
//
#include <hip/hip_runtime.h>

constexpr int BATCH = 8;
constexpr int PPC   = 2048;            // points per cloud
constexpr int NPT   = BATCH * PPC;     // 16384 points
constexpr int OCH   = 64;              // out channels (= in channels)
constexpr int KNN_K = 20;
constexpr int NEDGE = NPT * KNN_K;     // 327680 edges
constexpr int REVCAP = 128;            // per-row reverse-adjacency capacity
constexpr int OVCAP  = 8192;           // overflow list capacity

__device__ __forceinline__ int fmap(float f) {   // monotone float->signed-int map
  int i = __float_as_int(f);
  return i >= 0 ? i : (i ^ 0x7FFFFFFF);
}
__device__ __forceinline__ float funmap(int m) {
  int i = m >= 0 ? m : (m ^ 0x7FFFFFFF);
  return __int_as_float(i);
}

// ---------------------------------------------------------------- kNN ------
// Block = 16 points x 16 splits. 3 passes per lane (128 candidates each):
//  P1: u32 distance-only sorted top-20 via min/max_u32 (2 ops/slot).
//  P2: branch-free push of qualifiers (d2 <= kd[19]) into per-lane LDS stack.
//  P3: rank-based index placement (exact (d2, index) tie-break).
// Then width-16 shfl min-tournament merge on (d2,idx) and reverse-CSR fill.
__global__ __launch_bounds__(256) void knn_kernel(const float* __restrict__ pos,
                                                  int* __restrict__ nbr,
                                                  int* __restrict__ cnt,
                                                  int* __restrict__ ovf_cnt,
                                                  int* __restrict__ ovf,
                                                  int* __restrict__ rev) {
  __shared__ float4 cps[8 * 257];            // region r at r*257 (+pad)
  __shared__ unsigned short stk[24 * 256];   // per-lane qualifier stacks
  const int t  = threadIdx.x;
  const int pl = t >> 4;                     // point-local 0..15
  const int s  = t & 15;                     // split 0..15
  const int i  = blockIdx.x * 16 + pl;
  const int cbase = i & ~(PPC - 1);

  for (int u = t; u < PPC; u += 256) {
    int j = cbase + u;
    float ax = pos[3 * j], ay = pos[3 * j + 1], az = pos[3 * j + 2];
    cps[(u >> 8) * 257 + (u & 255)] = make_float4(ax, ay, az, ax * ax + ay * ay + az * az);
  }
  __syncthreads();

  const int il = i - cbase;
  const float4 me = cps[(il >> 8) * 257 + (il & 255)];
  const float px = me.x, py = me.y, pz = me.z, sqi = me.w;
  const int jbase = s * 128;
  const float4* __restrict__ cp = &cps[(s >> 1) * 257 + (s & 1) * 128];

  // ---- pass 1: distance-only sorted top-20 (u32, full-rate min/max) ----
  unsigned kd[KNN_K];
#pragma unroll
  for (int q = 0; q < KNN_K; ++q) kd[q] = 0xFFFFFFFFu;
  for (int u = 0; u < 128; ++u) {
    float4 c = cp[u];
    float d2 = sqi + c.w - 2.0f * (px * c.x + py * c.y + pz * c.z);
    d2 = d2 > 0.f ? d2 : 0.f;
    unsigned ck = __float_as_uint(d2);
    ck = (jbase + u == il) ? 0xFFFFFFFFu : ck;
#pragma unroll
    for (int q = KNN_K - 1; q > 0; --q) {
      unsigned lo = kd[q] < ck ? kd[q] : ck;
      kd[q] = kd[q - 1] > lo ? kd[q - 1] : lo;
    }
    kd[0] = kd[0] < ck ? kd[0] : ck;
  }
  const unsigned thr = kd[KNN_K - 1];

  // ---- pass 2: branch-free stack push of qualifiers ----
  int nq = 0;
  for (int u = 0; u < 128; ++u) {
    float4 c = cp[u];
    float d2 = sqi + c.w - 2.0f * (px * c.x + py * c.y + pz * c.z);
    d2 = d2 > 0.f ? d2 : 0.f;
    unsigned ck = __float_as_uint(d2);
    ck = (jbase + u == il) ? 0xFFFFFFFFu : ck;
    int slot = nq < 23 ? nq : 23;
    stk[slot * 256 + t] = (unsigned short)u;   // unconditional write
    nq += (ck <= thr) ? 1 : 0;                 // conditional advance
  }

  // wave-max of stack depth (uniform loop bound)
  int mc = nq;
#pragma unroll
  for (int m = 1; m < 64; m <<= 1) {
    int o = __shfl_xor(mc, m);
    mc = o > mc ? o : mc;
  }
  mc = mc < 24 ? mc : 24;

  // ---- pass 3: rank-based index placement ----
  unsigned idx[KNN_K];
#pragma unroll
  for (int q = 0; q < KNN_K; ++q) idx[q] = 0;
  unsigned prev_d2 = 0xFFFFFFFFu;
  int prev_off = 0;
  for (int n = 0; n < mc; ++n) {
    bool vld = n < nq;
    unsigned u = vld ? (unsigned)stk[n * 256 + t] : 0u;
    float4 c = cp[u & 127];
    float d2 = sqi + c.w - 2.0f * (px * c.x + py * c.y + pz * c.z);
    d2 = d2 > 0.f ? d2 : 0.f;
    unsigned d2u = vld ? __float_as_uint(d2) : 0xFFFFFFFFu;
    int rank = 0;
#pragma unroll
    for (int q = 0; q < KNN_K; ++q) rank += (kd[q] < d2u) ? 1 : 0;
    bool eq = (d2u == prev_d2);
    prev_off = eq ? prev_off + 1 : 0;
    rank += prev_off;
    prev_d2 = d2u;
    unsigned jl = jbase + u;
#pragma unroll
    for (int q = 0; q < KNN_K; ++q) idx[q] = (rank == q) ? jl : idx[q];
  }

  // ---- merge: 20 rounds of width-16 min-tournament on (d2, idx) ----
  int res[KNN_K];
#pragma unroll
  for (int r = 0; r < KNN_K; ++r) {
    unsigned wd = kd[0], wi = idx[0];
#pragma unroll
    for (int m = 1; m < 16; m <<= 1) {
      unsigned od = (unsigned)__shfl_xor((int)wd, m, 16);
      unsigned oi = (unsigned)__shfl_xor((int)wi, m, 16);
      bool less = (od < wd) || (od == wd && oi < wi);
      wd = less ? od : wd;
      wi = less ? oi : wi;
    }
    res[r] = (int)wi;
    bool mine = (kd[0] == wd) && (idx[0] == wi);
#pragma unroll
    for (int q = 0; q < KNN_K - 1; ++q) {
      kd[q]  = mine ? kd[q + 1]  : kd[q];
      idx[q] = mine ? idx[q + 1] : idx[q];
    }
    kd[KNN_K - 1]  = mine ? 0xFFFFFFFFu : kd[KNN_K - 1];
    idx[KNN_K - 1] = mine ? 0xFFFFFFFFu : idx[KNN_K - 1];
  }
  if (s == 0) {
    int4* op = reinterpret_cast<int4*>(&nbr[(size_t)i * KNN_K]);
#pragma unroll
    for (int q = 0; q < 5; ++q)
      op[q] = make_int4(cbase + res[4 * q], cbase + res[4 * q + 1],
                        cbase + res[4 * q + 2], cbase + res[4 * q + 3]);
  }
  // reverse-CSR fill from registers: lane s handles q = s (and s+16 if s<4)
#pragma unroll
  for (int q0 = 0; q0 < 2; ++q0) {
    int q = s + q0 * 16;
    if (q < KNN_K) {
      int j = cbase + res[q];
      int e = i * KNN_K + q;
      int slot = atomicAdd(&cnt[j], 1);
      if (slot < REVCAP) rev[j * REVCAP + slot] = e;
      else { int ov = atomicAdd(ovf_cnt, 1); if (ov < OVCAP) ovf[ov] = e; }
    }
  }
}

// ------------------------------------------------- node-level layer-1 GEMM -
__global__ __launch_bounds__(256) void node_gemm(const float* __restrict__ x,
                                                 const float* __restrict__ W1,
                                                 float* __restrict__ yv,
                                                 float* __restrict__ zv) {
  __shared__ float wa[64][65];
  __shared__ float wb[64][65];
  __shared__ float xs[4][64];
  const int t = threadIdx.x;
  for (int m = t; m < 8192; m += 256) {
    int o = m >> 7, c2 = m & 127;
    float w = W1[m];
    if (c2 < 64) wa[c2][o] = w; else wb[c2 - 64][o] = w;
  }
  const int nl = t >> 6, o = t & 63;
  xs[nl][o] = x[(size_t)(blockIdx.x * 4 + nl) * 64 + o];
  __syncthreads();
  float accA = 0.f, accB = 0.f;
#pragma unroll 8
  for (int c = 0; c < 64; ++c) {
    float xv = xs[nl][c];
    accA = fmaf(xv, wa[c][o], accA);
    accB = fmaf(xv, wb[c][o], accB);
  }
  size_t n = (size_t)blockIdx.x * 4 + nl;
  yv[n * 64 + o] = accA - accB;
  zv[n * 64 + o] = accB;
}

// ------------------------------------------------------------ BN1 stats ----
__global__ __launch_bounds__(256) void bn1_stats(const int* __restrict__ nbr,
                                                 const float4* __restrict__ yv4,
                                                 const float4* __restrict__ zv4,
                                                 const float* __restrict__ b1,
                                                 float* __restrict__ stats) {
  const int t  = threadIdx.x;
  const int c4 = t & 15;
  const int el = t >> 4;
  const float4 bo = reinterpret_cast<const float4*>(b1)[c4];
  float4 s1 = make_float4(0, 0, 0, 0), s2 = make_float4(0, 0, 0, 0);
#pragma unroll 4
  for (int e0 = blockIdx.x * 16; e0 < NEDGE; e0 += gridDim.x * 16) {
    int e  = e0 + el;
    int j  = nbr[e];
    int ic = e / KNN_K;
    float4 y = yv4[(size_t)j * 16 + c4];
    float4 z = zv4[(size_t)ic * 16 + c4];
    float sx = y.x + z.x + bo.x, sy = y.y + z.y + bo.y;
    float sz = y.z + z.z + bo.z, sw = y.w + z.w + bo.w;
    s1.x += sx; s1.y += sy; s1.z += sz; s1.w += sw;
    s2.x += sx * sx; s2.y += sy * sy; s2.z += sz * sz; s2.w += sw * sw;
  }
  s1.x += __shfl_xor(s1.x, 16); s1.y += __shfl_xor(s1.y, 16);
  s1.z += __shfl_xor(s1.z, 16); s1.w += __shfl_xor(s1.w, 16);
  s2.x += __shfl_xor(s2.x, 16); s2.y += __shfl_xor(s2.y, 16);
  s2.z += __shfl_xor(s2.z, 16); s2.w += __shfl_xor(s2.w, 16);
  s1.x += __shfl_xor(s1.x, 32); s1.y += __shfl_xor(s1.y, 32);
  s1.z += __shfl_xor(s1.z, 32); s1.w += __shfl_xor(s1.w, 32);
  s2.x += __shfl_xor(s2.x, 32); s2.y += __shfl_xor(s2.y, 32);
  s2.z += __shfl_xor(s2.z, 32); s2.w += __shfl_xor(s2.w, 32);
  __shared__ float ss[2][64];
  if (t < 128) { ss[0][t & 63] = 0.f; }
  __syncthreads();
  if ((t & 48) == 0) {
    atomicAdd(&ss[0][c4 * 4 + 0], s1.x); atomicAdd(&ss[0][c4 * 4 + 1], s1.y);
    atomicAdd(&ss[0][c4 * 4 + 2], s1.z); atomicAdd(&ss[0][c4 * 4 + 3], s1.w);
    atomicAdd(&ss[1][c4 * 4 + 0], s2.x); atomicAdd(&ss[1][c4 * 4 + 1], s2.y);
    atomicAdd(&ss[1][c4 * 4 + 2], s2.z); atomicAdd(&ss[1][c4 * 4 + 3], s2.w);
  }
  __syncthreads();
  if (t < 64)       atomicAdd(&stats[t], ss[0][t]);
  else if (t < 128) atomicAdd(&stats[64 + (t - 64)], ss[1][t - 64]);
}

// ------------- row-grouped GEMM2 + BN2 stats + per-row max/min (no h2s) ----
// Block owns 32 rows; iterates their reverse-adjacency edges in 64-edge
// tiles. Per-row max/min of raw h2_pre reduced in LDS (mapped-int atomics),
// plain-stored to global (exclusive row ownership). BN2 applied later via
// the monotone-affine identity in finalize_out.
__global__ __launch_bounds__(256) void gemm2_seg(
    const float4* __restrict__ yv4, const float4* __restrict__ zv4,
    const float* __restrict__ b1, const float* __restrict__ stats1,
    const float* __restrict__ g1, const float* __restrict__ beta1,
    const float* __restrict__ W2, const float* __restrict__ b2,
    const int* __restrict__ cnt, const int* __restrict__ rev,
    float* __restrict__ stats2, int* __restrict__ mmax, int* __restrict__ mmin) {
  __shared__ float w2t[64][68];
  __shared__ float h1s[64][68];
  __shared__ float a1s[64], c1s[64], b1s[64];
  __shared__ int   cct[32];
  __shared__ int   offs[33];
  __shared__ int   rowid[64];
  __shared__ int   maxt[32][64];
  __shared__ int   mint[32][64];
  __shared__ float ss[2][64];
  const int t = threadIdx.x;
  const int r0 = blockIdx.x * 32;
  constexpr float invE = 1.0f / NEDGE;
  for (int m = t; m < 4096; m += 256) {
    int o = m >> 6, c = m & 63;
    w2t[c][o] = W2[m];
  }
  if (t < 64) {
    float mu  = stats1[t] * invE;
    float var = stats1[64 + t] * invE - mu * mu;
    float a   = g1[t] * rsqrtf(var + 1e-5f);
    a1s[t] = a; c1s[t] = beta1[t] - mu * a; b1s[t] = b1[t];
  }
  if (t < 32) { int c = cnt[r0 + t]; cct[t] = c < REVCAP ? c : REVCAP; }
  __syncthreads();
  if (t == 0) {
    int a = 0;
    for (int r = 0; r < 32; ++r) { offs[r] = a; a += cct[r]; }
    offs[32] = a;
  }
  for (int m = t; m < 2048; m += 256) {
    (&maxt[0][0])[m] = 0x80000000;
    (&mint[0][0])[m] = 0x7FFFFFFF;
  }
  __syncthreads();
  const int total = offs[32];
  const int eg = t >> 4, cg = t & 15;
  const int e0l = eg * 4, o0 = cg * 4;
  float b2r[4], a1r[4], c1r[4], b1r[4];
#pragma unroll
  for (int q = 0; q < 4; ++q) {
    b2r[q] = b2[o0 + q];
    a1r[q] = a1s[o0 + q]; c1r[q] = c1s[o0 + q]; b1r[q] = b1s[o0 + q];
  }
  float s1[4] = {0, 0, 0, 0}, s2[4] = {0, 0, 0, 0};
  const int ntiles = (total + 63) >> 6;
  for (int ti = 0; ti < ntiles; ++ti) {
    __syncthreads();
#pragma unroll
    for (int k = 0; k < 4; ++k) {
      int el = k * 16 + eg;
      int m  = ti * 64 + el;
      bool valid = m < total;
      int lo = 0, hi = 32;
#pragma unroll
      for (int st = 0; st < 5; ++st) {
        int mid = (lo + hi) >> 1;
        if (m >= offs[mid]) lo = mid; else hi = mid;
      }
      int r = lo;
      int e = 0;
      if (valid) e = rev[(size_t)(r0 + r) * REVCAP + (m - offs[r])];
      int j  = r0 + r;               // row == neighbor index for edges in rev[row]
      int ic = e / KNN_K;
      float4 y = yv4[(size_t)j * 16 + cg];
      float4 z = zv4[(size_t)ic * 16 + cg];
      float4 h;
      h.x = fmaf(y.x + z.x + b1r[0], a1r[0], c1r[0]);
      h.y = fmaf(y.y + z.y + b1r[1], a1r[1], c1r[1]);
      h.z = fmaf(y.z + z.z + b1r[2], a1r[2], c1r[2]);
      h.w = fmaf(y.w + z.w + b1r[3], a1r[3], c1r[3]);
      h.x = h.x > 0.f ? h.x : 0.f; h.y = h.y > 0.f ? h.y : 0.f;
      h.z = h.z > 0.f ? h.z : 0.f; h.w = h.w > 0.f ? h.w : 0.f;
      *reinterpret_cast<float4*>(&h1s[el][o0]) = h;
      if (cg == 0) rowid[el] = valid ? r : -1;
    }
    __syncthreads();
    float acc[4][4];
#pragma unroll
    for (int r = 0; r < 4; ++r)
#pragma unroll
      for (int q = 0; q < 4; ++q) acc[r][q] = 0.f;
#pragma unroll 4
    for (int c4 = 0; c4 < 16; ++c4) {
      float4 h0 = *reinterpret_cast<const float4*>(&h1s[e0l + 0][c4 * 4]);
      float4 h1 = *reinterpret_cast<const float4*>(&h1s[e0l + 1][c4 * 4]);
      float4 h2 = *reinterpret_cast<const float4*>(&h1s[e0l + 2][c4 * 4]);
      float4 h3 = *reinterpret_cast<const float4*>(&h1s[e0l + 3][c4 * 4]);
      float4 w0 = *reinterpret_cast<const float4*>(&w2t[c4 * 4 + 0][o0]);
      float4 w1 = *reinterpret_cast<const float4*>(&w2t[c4 * 4 + 1][o0]);
      float4 w2 = *reinterpret_cast<const float4*>(&w2t[c4 * 4 + 2][o0]);
      float4 w3 = *reinterpret_cast<const float4*>(&w2t[c4 * 4 + 3][o0]);
#define GFMA(R, H)                                                       \
      acc[R][0] = fmaf(H.x, w0.x, acc[R][0]); acc[R][0] = fmaf(H.y, w1.x, acc[R][0]); \
      acc[R][0] = fmaf(H.z, w2.x, acc[R][0]); acc[R][0] = fmaf(H.w, w3.x, acc[R][0]); \
      acc[R][1] = fmaf(H.x, w0.y, acc[R][1]); acc[R][1] = fmaf(H.y, w1.y, acc[R][1]); \
      acc[R][1] = fmaf(H.z, w2.y, acc[R][1]); acc[R][1] = fmaf(H.w, w3.y, acc[R][1]); \
      acc[R][2] = fmaf(H.x, w0.z, acc[R][2]); acc[R][2] = fmaf(H.y, w1.z, acc[R][2]); \
      acc[R][2] = fmaf(H.z, w2.z, acc[R][2]); acc[R][2] = fmaf(H.w, w3.z, acc[R][2]); \
      acc[R][3] = fmaf(H.x, w0.w, acc[R][3]); acc[R][3] = fmaf(H.y, w1.w, acc[R][3]); \
      acc[R][3] = fmaf(H.z, w2.w, acc[R][3]); acc[R][3] = fmaf(H.w, w3.w, acc[R][3]);
      GFMA(0, h0) GFMA(1, h1) GFMA(2, h2) GFMA(3, h3)
#undef GFMA
    }
    // epilogue: stats + run-merged LDS max/min atomics
    int cur = -1;
    float mx[4], mn[4];
#pragma unroll
    for (int r = 0; r < 4; ++r) {
      int rw = rowid[e0l + r];
      float v[4];
#pragma unroll
      for (int q = 0; q < 4; ++q) v[q] = acc[r][q] + b2r[q];
      if (rw >= 0) {
#pragma unroll
        for (int q = 0; q < 4; ++q) { s1[q] += v[q]; s2[q] += v[q] * v[q]; }
      }
      if (rw != cur) {
        if (cur >= 0) {
#pragma unroll
          for (int q = 0; q < 4; ++q) {
            atomicMax(&maxt[cur][o0 + q], fmap(mx[q]));
            atomicMin(&mint[cur][o0 + q], fmap(mn[q]));
          }
        }
        cur = rw;
#pragma unroll
        for (int q = 0; q < 4; ++q) { mx[q] = v[q]; mn[q] = v[q]; }
      } else if (rw >= 0) {
#pragma unroll
        for (int q = 0; q < 4; ++q) {
          mx[q] = v[q] > mx[q] ? v[q] : mx[q];
          mn[q] = v[q] < mn[q] ? v[q] : mn[q];
        }
      }
    }
    if (cur >= 0) {
#pragma unroll
      for (int q = 0; q < 4; ++q) {
        atomicMax(&maxt[cur][o0 + q], fmap(mx[q]));
        atomicMin(&mint[cur][o0 + q], fmap(mn[q]));
      }
    }
  }
  __syncthreads();
  // exclusive-owner plain stores of the row tables
  for (int m = t; m < 2048; m += 256) {
    int r = m >> 6, c = m & 63;
    mmax[(size_t)(r0 + r) * 64 + c] = maxt[r][c];
    mmin[(size_t)(r0 + r) * 64 + c] = mint[r][c];
  }
  // BN2 stats reduction
  if (t < 64) { ss[0][t] = 0.f; ss[1][t] = 0.f; }
  __syncthreads();
#pragma unroll
  for (int q = 0; q < 4; ++q) {
    s1[q] += __shfl_xor(s1[q], 16);
    s1[q] += __shfl_xor(s1[q], 32);
    s2[q] += __shfl_xor(s2[q], 16);
    s2[q] += __shfl_xor(s2[q], 32);
  }
  if ((t & 48) == 0) {
#pragma unroll
    for (int q = 0; q < 4; ++q) {
      atomicAdd(&ss[0][o0 + q], s1[q]);
      atomicAdd(&ss[1][o0 + q], s2[q]);
    }
  }
  __syncthreads();
  if (t < 64)       atomicAdd(&stats2[t], ss[0][t]);
  else if (t < 128) atomicAdd(&stats2[t - 64 + 64], ss[1][t - 64]);
}

// ---------------- finalize: BN2 affine of per-row max/min + relu + empties -
__global__ __launch_bounds__(256) void finalize_out(
    const float* __restrict__ stats2, const float* __restrict__ g2,
    const float* __restrict__ beta2, const int* __restrict__ cnt,
    const int* __restrict__ mmax, const int* __restrict__ mmin,
    const int* __restrict__ ovf_cnt, const int* __restrict__ ovf,
    const int* __restrict__ nbr, const float* __restrict__ yv,
    const float* __restrict__ zv, const float* __restrict__ b1,
    const float* __restrict__ stats1, const float* __restrict__ g1,
    const float* __restrict__ beta1, const float* __restrict__ W2,
    const float* __restrict__ b2, float* __restrict__ outp) {
  const int idx = blockIdx.x * 256 + threadIdx.x;
  const int row = idx >> 6, ch = idx & 63;
  constexpr float invE = 1.0f / NEDGE;
  float mu  = stats2[ch] * invE;
  float var = stats2[64 + ch] * invE - mu * mu;
  float a2  = g2[ch] * rsqrtf(var + 1e-5f);
  float c2  = beta2[ch] - mu * a2;
  float h = (a2 >= 0.f) ? funmap(mmax[idx]) : funmap(mmin[idx]);
  int ov = ovf_cnt[0]; ov = ov > OVCAP ? OVCAP : ov;
  for (int u = 0; u < ov; ++u) {      // overflow edges: recompute (rare/never)
    int e = ovf[u];
    if (nbr[e] == row) {
      int ic = e / KNN_K;
      float accv = 0.f;
      for (int k = 0; k < 64; ++k) {
        float mu1  = stats1[k] * invE;
        float var1 = stats1[64 + k] * invE - mu1 * mu1;
        float a1   = g1[k] * rsqrtf(var1 + 1e-5f);
        float c1   = beta1[k] - mu1 * a1;
        float sI   = yv[(size_t)row * 64 + k] + zv[(size_t)ic * 64 + k] + b1[k];
        float hh   = fmaf(sI, a1, c1);
        hh = hh > 0.f ? hh : 0.f;
        accv = fmaf(hh, W2[ch * 64 + k], accv);
      }
      float v = accv + b2[ch];
      if (a2 >= 0.f) h = v > h ? v : h; else h = v < h ? v : h;
    }
  }
  float o = (cnt[row] > 0) ? fmaf(h, a2, c2) : 0.0f;
  outp[idx] = o > 0.f ? o : 0.f;
}

// ---------------- fallback (small workspace): edge-tile GEMM2 two-pass -----
template <int MODE>
__global__ __launch_bounds__(256) void gemm2_pass(
    const int* __restrict__ nbr, const float* __restrict__ yv,
    const float* __restrict__ zv, const float* __restrict__ b1,
    const float* __restrict__ stats1, const float* __restrict__ g1,
    const float* __restrict__ beta1, const float* __restrict__ W2,
    const float* __restrict__ b2, float* __restrict__ stats2,
    const float* __restrict__ g2, const float* __restrict__ beta2,
    float* __restrict__ outp) {
  __shared__ float w2t[64][68];
  __shared__ float h1s[64][68];
  __shared__ float a1s[64], c1s[64], b1s[64];
  __shared__ float ss[2][64];
  const int t = threadIdx.x;
  constexpr float invE = 1.0f / NEDGE;
  const float4* __restrict__ yv4 = (const float4*)yv;
  const float4* __restrict__ zv4 = (const float4*)zv;
  for (int m = t; m < 4096; m += 256) {
    int o = m >> 6, c = m & 63;
    w2t[c][o] = W2[m];
  }
  if (t < 64) {
    float mu  = stats1[t] * invE;
    float var = stats1[64 + t] * invE - mu * mu;
    float a   = g1[t] * rsqrtf(var + 1e-5f);
    a1s[t] = a; c1s[t] = beta1[t] - mu * a; b1s[t] = b1[t];
  }
  __syncthreads();
  const int eg = t >> 4, cg = t & 15;
  const int e0l = eg * 4, o0 = cg * 4;
  float b2r[4], a2r[4], c2r[4], a1r[4], c1r[4], b1r[4];
#pragma unroll
  for (int q = 0; q < 4; ++q) {
    b2r[q] = b2[o0 + q];
    a1r[q] = a1s[o0 + q]; c1r[q] = c1s[o0 + q]; b1r[q] = b1s[o0 + q];
  }
  if (MODE == 1) {
#pragma unroll
    for (int q = 0; q < 4; ++q) {
      float mu  = stats2[o0 + q] * invE;
      float var = stats2[64 + o0 + q] * invE - mu * mu;
      float a   = g2[o0 + q] * rsqrtf(var + 1e-5f);
      a2r[q] = a; c2r[q] = beta2[o0 + q] - mu * a;
    }
  }
  float s1[4] = {0, 0, 0, 0}, s2[4] = {0, 0, 0, 0};
  const int ntiles = NEDGE / 64;
  for (int tile = blockIdx.x; tile < ntiles; tile += gridDim.x) {
    __syncthreads();
    const int ebase = tile * 64;
#pragma unroll
    for (int k = 0; k < 4; ++k) {
      int el = k * 16 + eg;
      int e  = ebase + el;
      int j  = nbr[e];
      int ic = e / KNN_K;
      float4 y = yv4[(size_t)j * 16 + cg];
      float4 z = zv4[(size_t)ic * 16 + cg];
      float4 h;
      h.x = fmaf(y.x + z.x + b1r[0], a1r[0], c1r[0]);
      h.y = fmaf(y.y + z.y + b1r[1], a1r[1], c1r[1]);
      h.z = fmaf(y.z + z.z + b1r[2], a1r[2], c1r[2]);
      h.w = fmaf(y.w + z.w + b1r[3], a1r[3], c1r[3]);
      h.x = h.x > 0.f ? h.x : 0.f; h.y = h.y > 0.f ? h.y : 0.f;
      h.z = h.z > 0.f ? h.z : 0.f; h.w = h.w > 0.f ? h.w : 0.f;
      *reinterpret_cast<float4*>(&h1s[el][o0]) = h;
    }
    __syncthreads();
    float acc[4][4];
#pragma unroll
    for (int r = 0; r < 4; ++r)
#pragma unroll
      for (int q = 0; q < 4; ++q) acc[r][q] = 0.f;
#pragma unroll 4
    for (int c4 = 0; c4 < 16; ++c4) {
      float4 h0 = *reinterpret_cast<const float4*>(&h1s[e0l + 0][c4 * 4]);
      float4 h1 = *reinterpret_cast<const float4*>(&h1s[e0l + 1][c4 * 4]);
      float4 h2 = *reinterpret_cast<const float4*>(&h1s[e0l + 2][c4 * 4]);
      float4 h3 = *reinterpret_cast<const float4*>(&h1s[e0l + 3][c4 * 4]);
      float4 w0 = *reinterpret_cast<const float4*>(&w2t[c4 * 4 + 0][o0]);
      float4 w1 = *reinterpret_cast<const float4*>(&w2t[c4 * 4 + 1][o0]);
      float4 w2 = *reinterpret_cast<const float4*>(&w2t[c4 * 4 + 2][o0]);
      float4 w3 = *reinterpret_cast<const float4*>(&w2t[c4 * 4 + 3][o0]);
#define GFMA(R, H)                                                       \
      acc[R][0] = fmaf(H.x, w0.x, acc[R][0]); acc[R][0] = fmaf(H.y, w1.x, acc[R][0]); \
      acc[R][0] = fmaf(H.z, w2.x, acc[R][0]); acc[R][0] = fmaf(H.w, w3.x, acc[R][0]); \
      acc[R][1] = fmaf(H.x, w0.y, acc[R][1]); acc[R][1] = fmaf(H.y, w1.y, acc[R][1]); \
      acc[R][1] = fmaf(H.z, w2.y, acc[R][1]); acc[R][1] = fmaf(H.w, w3.y, acc[R][1]); \
      acc[R][2] = fmaf(H.x, w0.z, acc[R][2]); acc[R][2] = fmaf(H.y, w1.z, acc[R][2]); \
      acc[R][2] = fmaf(H.z, w2.z, acc[R][2]); acc[R][2] = fmaf(H.w, w3.z, acc[R][2]); \
      acc[R][3] = fmaf(H.x, w0.w, acc[R][3]); acc[R][3] = fmaf(H.y, w1.w, acc[R][3]); \
      acc[R][3] = fmaf(H.z, w2.w, acc[R][3]); acc[R][3] = fmaf(H.w, w3.w, acc[R][3]);
      GFMA(0, h0) GFMA(1, h1) GFMA(2, h2) GFMA(3, h3)
#undef GFMA
    }
    if constexpr (MODE == 0) {
#pragma unroll
      for (int r = 0; r < 4; ++r) {
#pragma unroll
        for (int q = 0; q < 4; ++q) {
          float v = acc[r][q] + b2r[q];
          s1[q] += v; s2[q] += v * v;
        }
      }
    } else {
#pragma unroll
      for (int r = 0; r < 4; ++r) {
        int row = nbr[ebase + e0l + r];
        int* op = reinterpret_cast<int*>(outp) + (size_t)row * 64 + o0;
#pragma unroll
        for (int q = 0; q < 4; ++q) {
          float v = fmaf(acc[r][q] + b2r[q], a2r[q], c2r[q]);
          v = v > 0.f ? v : 0.f;
          atomicMax(op + q, __float_as_int(v));
        }
      }
    }
  }
  if constexpr (MODE == 0) {
    __syncthreads();
    if (t < 64) { ss[0][t] = 0.f; ss[1][t] = 0.f; }
    __syncthreads();
#pragma unroll
    for (int q = 0; q < 4; ++q) {
      s1[q] += __shfl_xor(s1[q], 16);
      s1[q] += __shfl_xor(s1[q], 32);
      s2[q] += __shfl_xor(s2[q], 16);
      s2[q] += __shfl_xor(s2[q], 32);
    }
    if ((t & 48) == 0) {
#pragma unroll
      for (int q = 0; q < 4; ++q) {
        atomicAdd(&ss[0][o0 + q], s1[q]);
        atomicAdd(&ss[1][o0 + q], s2[q]);
      }
    }
    __syncthreads();
    if (t < 64)       atomicAdd(&stats2[t], ss[0][t]);
    else if (t < 128) atomicAdd(&stats2[t - 64 + 64], ss[1][t - 64]);
  }
}

// --------------------------------------------------------------- launch ----
extern "C" void kernel_launch(void* const* d_in, const int* in_sizes, int n_in,
                              void* d_out, int out_size, void* d_ws, size_t ws_size,
                              hipStream_t stream) {
  (void)in_sizes; (void)n_in;
  const float* x     = (const float*)d_in[0];
  const float* pos   = (const float*)d_in[1];
  const float* W1    = (const float*)d_in[3];
  const float* b1    = (const float*)d_in[4];
  const float* g1    = (const float*)d_in[5];
  const float* beta1 = (const float*)d_in[6];
  const float* W2    = (const float*)d_in[7];
  const float* b2    = (const float*)d_in[8];
  const float* g2    = (const float*)d_in[9];
  const float* beta2 = (const float*)d_in[10];
  float* outp = (float*)d_out;

  char* w = (char*)d_ws;
  int*   nbr     = (int*)w;                            // 1,310,720 B
  float* yv      = (float*)(w + 1310720);              // 4,194,304 B
  float* zv      = (float*)(w + 5505024);              // 4,194,304 B
  float* stats   = (float*)(w + 9699328);              // 1,024 B
  int*   cnt     = (int*)(w + 9700352);                // 65,536 B
  int*   ovf_cnt = (int*)(w + 9765888);                // 64 B
  int*   ovf     = (int*)(w + 9765952);                // 32,768 B
  int*   rev     = (int*)(w + 9798720);                // 8,388,608 B -> 18,187,328
  int*   mmax    = (int*)(w + 18187328);               // 4,194,304 B
  int*   mmin    = (int*)(w + 22381632);               // 4,194,304 B -> 26,575,936
  const size_t NEED_BIG = 26575936ull;
  const bool big = ws_size >= NEED_BIG;

  hipMemsetAsync(stats, 0, 1024, stream);
  hipMemsetAsync(cnt, 0, 65536 + 64, stream);

  knn_kernel<<<NPT / 16, 256, 0, stream>>>(pos, nbr, cnt, ovf_cnt, ovf, rev);
  node_gemm<<<NPT / 4, 256, 0, stream>>>(x, W1, yv, zv);
  bn1_stats<<<512, 256, 0, stream>>>(nbr, (const float4*)yv, (const float4*)zv, b1, stats);
  if (big) {
    gemm2_seg<<<NPT / 32, 256, 0, stream>>>(
        (const float4*)yv, (const float4*)zv, b1, stats, g1, beta1, W2, b2,
        cnt, rev, stats + 128, mmax, mmin);
    finalize_out<<<NPT * 64 / 256, 256, 0, stream>>>(
        stats + 128, g2, beta2, cnt, mmax, mmin, ovf_cnt, ovf, nbr,
        yv, zv, b1, stats, g1, beta1, W2, b2, outp);
  } else {
    hipMemsetAsync(d_out, 0, (size_t)out_size * sizeof(float), stream);
    gemm2_pass<0><<<1024, 256, 0, stream>>>(
        nbr, yv, zv, b1, stats, g1, beta1, W2, b2, stats + 128, g2, beta2, nullptr);
    gemm2_pass<1><<<1024, 256, 0, stream>>>(
        nbr, yv, zv, b1, stats, g1, beta1, W2, b2, stats + 128, g2, beta2, outp);
  }
}

// Round 7
// 285.197 us; speedup vs baseline: 1.1392x; 1.1392x over previous
//
#include <hip/hip_runtime.h>

constexpr int BATCH = 8;
constexpr int PPC   = 2048;            // points per cloud
constexpr int NPT   = BATCH * PPC;     // 16384 points
constexpr int OCH   = 64;              // out channels (= in channels)
constexpr int KNN_K = 20;
constexpr int NEDGE = NPT * KNN_K;     // 327680 edges
constexpr int REVCAP = 128;            // per-row reverse-adjacency capacity
constexpr int OVCAP  = 8192;           // overflow list capacity
constexpr int QCAP   = 44;             // per-point qualifier capacity

__device__ __forceinline__ int fmap(float f) {   // monotone float->signed-int map
  int i = __float_as_int(f);
  return i >= 0 ? i : (i ^ 0x7FFFFFFF);
}
__device__ __forceinline__ float funmap(int m) {
  int i = m >= 0 ? m : (m ^ 0x7FFFFFFF);
  return __int_as_float(i);
}

__device__ __forceinline__ unsigned umed3(unsigned a, unsigned b, unsigned c) {
  unsigned d;
  asm("v_med3_u32 %0, %1, %2, %3" : "=v"(d) : "v"(a), "v"(b), "v"(c));
  return d;
}

// ---------------------------------------------------------------- kNN ------
// Block = 16 points x 16 splits (256 threads).
// P1: per-lane sorted top-20 DISTANCES via v_med3_u32 (1 op/slot:
//     kd[q] = med3(kd[q-1], kd[q], ck) == max(kd[q-1], min(kd[q], ck))).
// Merge: width-16 min-tournament with pop-all-ties -> global 20th value T.
// P2: push candidates with d2u<=T (~20/point) as u64 (d2,idx) into LDS.
// P3: exact rank by pairwise u64 compare (== jax top_k (d2,index) order);
//     emit nbr + reverse-CSR from the ranked entries.
__global__ __launch_bounds__(256) void knn_kernel(const float* __restrict__ pos,
                                                  int* __restrict__ nbr,
                                                  int* __restrict__ cnt,
                                                  int* __restrict__ ovf_cnt,
                                                  int* __restrict__ ovf,
                                                  int* __restrict__ rev) {
  __shared__ float4 cps[8 * 257];                 // region r at r*257 (+pad)
  __shared__ unsigned long long qk[16][QCAP];     // per-point qualifiers
  __shared__ int qn[16];
  const int t  = threadIdx.x;
  const int pl = t >> 4;                     // point-local 0..15
  const int s  = t & 15;                     // split 0..15
  const int lane = t & 63;
  const int i  = blockIdx.x * 16 + pl;
  const int cbase = i & ~(PPC - 1);

  for (int u = t; u < PPC; u += 256) {
    int j = cbase + u;
    float ax = pos[3 * j], ay = pos[3 * j + 1], az = pos[3 * j + 2];
    cps[(u >> 8) * 257 + (u & 255)] = make_float4(ax, ay, az, ax * ax + ay * ay + az * az);
  }
  if (t < 16) qn[t] = 0;
  __syncthreads();

  const int il = i - cbase;
  const float4 me = cps[(il >> 8) * 257 + (il & 255)];
  const float px = me.x, py = me.y, pz = me.z, sqi = me.w;
  const int jbase = s * 128;
  const float4* __restrict__ cp = &cps[(s >> 1) * 257 + (s & 1) * 128];

  // ---- pass 1: distance-only sorted top-20 via med3 ----
  unsigned kd[KNN_K];
#pragma unroll
  for (int q = 0; q < KNN_K; ++q) kd[q] = 0xFFFFFFFFu;
  for (int u = 0; u < 128; ++u) {
    float4 c = cp[u];
    float d2 = sqi + c.w - 2.0f * (px * c.x + py * c.y + pz * c.z);
    d2 = d2 > 0.f ? d2 : 0.f;
    unsigned ck = __float_as_uint(d2);
    ck = (jbase + u == il) ? 0xFFFFFFFFu : ck;
#pragma unroll
    for (int q = KNN_K - 1; q > 0; --q) kd[q] = umed3(kd[q - 1], kd[q], ck);
    kd[0] = kd[0] < ck ? kd[0] : ck;
  }

  // ---- merge: global 20th-smallest distance T (pop-all-ties) ----
  unsigned T = 0xFFFFFFFFu;
  int cum = 0;
  const int grp = lane & 48;
#pragma unroll
  for (int r = 0; r < KNN_K; ++r) {
    unsigned w = kd[0];
#pragma unroll
    for (int m = 1; m < 16; m <<= 1) {
      unsigned o = (unsigned)__shfl_xor((int)w, m, 16);
      w = o < w ? o : w;
    }
    bool pop = (kd[0] == w);
    unsigned long long bal = __ballot(pop);
    int mcount = __popc((int)((bal >> grp) & 0xFFFFull));
    if (cum < KNN_K) T = w;
    cum += mcount;
    if (pop) {
#pragma unroll
      for (int q = 0; q < KNN_K - 1; ++q) kd[q] = kd[q + 1];
      kd[KNN_K - 1] = 0xFFFFFFFFu;
    }
  }

  // ---- pass 2: push qualifiers (d2u <= T) ----
  for (int u = 0; u < 128; ++u) {
    float4 c = cp[u];
    float d2 = sqi + c.w - 2.0f * (px * c.x + py * c.y + pz * c.z);
    d2 = d2 > 0.f ? d2 : 0.f;
    unsigned ck = __float_as_uint(d2);
    ck = (jbase + u == il) ? 0xFFFFFFFFu : ck;
    if (ck <= T) {
      int slot = atomicAdd(&qn[pl], 1);
      if (slot < QCAP)
        qk[pl][slot] = ((unsigned long long)ck << 32) | (unsigned)(jbase + u);
    }
  }
  __syncthreads();

  // ---- pass 3: exact rank + emit nbr/rev ----
  int n = qn[pl]; n = n < QCAP ? n : QCAP;
  for (int base = 0; base < n; base += 16) {
    int e = base + s;
    if (e < n) {
      unsigned long long mk = qk[pl][e];
      int rank = 0;
      for (int o = 0; o < n; ++o) rank += (qk[pl][o] < mk) ? 1 : 0;
      if (rank < KNN_K) {
        int j = cbase + (int)(mk & 0xFFFFFFFFull);
        int eid = i * KNN_K + rank;
        nbr[eid] = j;
        int slot = atomicAdd(&cnt[j], 1);
        if (slot < REVCAP) rev[j * REVCAP + slot] = eid;
        else { int ov = atomicAdd(ovf_cnt, 1); if (ov < OVCAP) ovf[ov] = eid; }
      }
    }
  }
}

// ------------------------------------------------- node-level layer-1 GEMM -
__global__ __launch_bounds__(256) void node_gemm(const float* __restrict__ x,
                                                 const float* __restrict__ W1,
                                                 float* __restrict__ yv,
                                                 float* __restrict__ zv) {
  __shared__ float wa[64][65];
  __shared__ float wb[64][65];
  __shared__ float xs[4][64];
  const int t = threadIdx.x;
  for (int m = t; m < 8192; m += 256) {
    int o = m >> 7, c2 = m & 127;
    float w = W1[m];
    if (c2 < 64) wa[c2][o] = w; else wb[c2 - 64][o] = w;
  }
  const int nl = t >> 6, o = t & 63;
  xs[nl][o] = x[(size_t)(blockIdx.x * 4 + nl) * 64 + o];
  __syncthreads();
  float accA = 0.f, accB = 0.f;
#pragma unroll 8
  for (int c = 0; c < 64; ++c) {
    float xv = xs[nl][c];
    accA = fmaf(xv, wa[c][o], accA);
    accB = fmaf(xv, wb[c][o], accB);
  }
  size_t n = (size_t)blockIdx.x * 4 + nl;
  yv[n * 64 + o] = accA - accB;
  zv[n * 64 + o] = accB;
}

// ---------------------------- BN1 stats: center-grouped (z once, 20 y rows) -
__global__ __launch_bounds__(256) void bn1_stats(const int* __restrict__ nbr,
                                                 const float4* __restrict__ yv4,
                                                 const float4* __restrict__ zv4,
                                                 const float* __restrict__ b1,
                                                 float* __restrict__ stats) {
  const int t  = threadIdx.x;
  const int c4 = t & 15;
  const int lane = t & 63;
  const int i  = blockIdx.x * 16 + (t >> 4);
  const float4 bo = reinterpret_cast<const float4*>(b1)[c4];
  float4 z = zv4[(size_t)i * 16 + c4];
  float4 zb = make_float4(z.x + bo.x, z.y + bo.y, z.z + bo.z, z.w + bo.w);
  int jA = nbr[i * KNN_K + c4];
  int jB = nbr[i * KNN_K + 16 + (c4 & 3)];
  float4 s1 = make_float4(0, 0, 0, 0), s2 = make_float4(0, 0, 0, 0);
#pragma unroll
  for (int q = 0; q < 16; ++q) {
    int j = __shfl(jA, (lane & 48) + q);
    float4 y = yv4[(size_t)j * 16 + c4];
    float sx = y.x + zb.x, sy = y.y + zb.y, sz = y.z + zb.z, sw = y.w + zb.w;
    s1.x += sx; s1.y += sy; s1.z += sz; s1.w += sw;
    s2.x += sx * sx; s2.y += sy * sy; s2.z += sz * sz; s2.w += sw * sw;
  }
#pragma unroll
  for (int q = 0; q < 4; ++q) {
    int j = __shfl(jB, (lane & 48) + q);
    float4 y = yv4[(size_t)j * 16 + c4];
    float sx = y.x + zb.x, sy = y.y + zb.y, sz = y.z + zb.z, sw = y.w + zb.w;
    s1.x += sx; s1.y += sy; s1.z += sz; s1.w += sw;
    s2.x += sx * sx; s2.y += sy * sy; s2.z += sz * sz; s2.w += sw * sw;
  }
  s1.x += __shfl_xor(s1.x, 16); s1.y += __shfl_xor(s1.y, 16);
  s1.z += __shfl_xor(s1.z, 16); s1.w += __shfl_xor(s1.w, 16);
  s2.x += __shfl_xor(s2.x, 16); s2.y += __shfl_xor(s2.y, 16);
  s2.z += __shfl_xor(s2.z, 16); s2.w += __shfl_xor(s2.w, 16);
  s1.x += __shfl_xor(s1.x, 32); s1.y += __shfl_xor(s1.y, 32);
  s1.z += __shfl_xor(s1.z, 32); s1.w += __shfl_xor(s1.w, 32);
  s2.x += __shfl_xor(s2.x, 32); s2.y += __shfl_xor(s2.y, 32);
  s2.z += __shfl_xor(s2.z, 32); s2.w += __shfl_xor(s2.w, 32);
  __shared__ float ss[2][64];
  if (t < 128) { ss[0][t & 63] = 0.f; }
  __syncthreads();
  if ((t & 48) == 0) {
    atomicAdd(&ss[0][c4 * 4 + 0], s1.x); atomicAdd(&ss[0][c4 * 4 + 1], s1.y);
    atomicAdd(&ss[0][c4 * 4 + 2], s1.z); atomicAdd(&ss[0][c4 * 4 + 3], s1.w);
    atomicAdd(&ss[1][c4 * 4 + 0], s2.x); atomicAdd(&ss[1][c4 * 4 + 1], s2.y);
    atomicAdd(&ss[1][c4 * 4 + 2], s2.z); atomicAdd(&ss[1][c4 * 4 + 3], s2.w);
  }
  __syncthreads();
  if (t < 64)       atomicAdd(&stats[t], ss[0][t]);
  else if (t < 128) atomicAdd(&stats[64 + (t - 64)], ss[1][t - 64]);
}

// ------------- row-grouped GEMM2 + BN2 stats + per-row max/min (no h2s) ----
__global__ __launch_bounds__(256) void gemm2_seg(
    const float4* __restrict__ yv4, const float4* __restrict__ zv4,
    const float* __restrict__ b1, const float* __restrict__ stats1,
    const float* __restrict__ g1, const float* __restrict__ beta1,
    const float* __restrict__ W2, const float* __restrict__ b2,
    const int* __restrict__ cnt, const int* __restrict__ rev,
    float* __restrict__ stats2, int* __restrict__ mmax, int* __restrict__ mmin) {
  __shared__ float w2t[64][68];
  __shared__ float h1s[64][68];
  __shared__ float a1s[64], c1s[64], b1s[64];
  __shared__ int   cct[32];
  __shared__ int   offs[33];
  __shared__ int   rowid[64];
  __shared__ int   maxt[32][64];
  __shared__ int   mint[32][64];
  __shared__ float ss[2][64];
  const int t = threadIdx.x;
  const int r0 = blockIdx.x * 32;
  constexpr float invE = 1.0f / NEDGE;
  for (int m = t; m < 4096; m += 256) {
    int o = m >> 6, c = m & 63;
    w2t[c][o] = W2[m];
  }
  if (t < 64) {
    float mu  = stats1[t] * invE;
    float var = stats1[64 + t] * invE - mu * mu;
    float a   = g1[t] * rsqrtf(var + 1e-5f);
    a1s[t] = a; c1s[t] = beta1[t] - mu * a; b1s[t] = b1[t];
  }
  if (t < 32) { int c = cnt[r0 + t]; cct[t] = c < REVCAP ? c : REVCAP; }
  __syncthreads();
  if (t == 0) {
    int a = 0;
    for (int r = 0; r < 32; ++r) { offs[r] = a; a += cct[r]; }
    offs[32] = a;
  }
  for (int m = t; m < 2048; m += 256) {
    (&maxt[0][0])[m] = 0x80000000;
    (&mint[0][0])[m] = 0x7FFFFFFF;
  }
  __syncthreads();
  const int total = offs[32];
  const int eg = t >> 4, cg = t & 15;
  const int e0l = eg * 4, o0 = cg * 4;
  float b2r[4], a1r[4], c1r[4], b1r[4];
#pragma unroll
  for (int q = 0; q < 4; ++q) {
    b2r[q] = b2[o0 + q];
    a1r[q] = a1s[o0 + q]; c1r[q] = c1s[o0 + q]; b1r[q] = b1s[o0 + q];
  }
  float s1[4] = {0, 0, 0, 0}, s2[4] = {0, 0, 0, 0};
  const int ntiles = (total + 63) >> 6;
  for (int ti = 0; ti < ntiles; ++ti) {
    __syncthreads();
#pragma unroll
    for (int k = 0; k < 4; ++k) {
      int el = k * 16 + eg;
      int m  = ti * 64 + el;
      bool valid = m < total;
      int lo = 0, hi = 32;
#pragma unroll
      for (int st = 0; st < 5; ++st) {
        int mid = (lo + hi) >> 1;
        if (m >= offs[mid]) lo = mid; else hi = mid;
      }
      int r = lo;
      int e = 0;
      if (valid) e = rev[(size_t)(r0 + r) * REVCAP + (m - offs[r])];
      int j  = r0 + r;
      int ic = e / KNN_K;
      float4 y = yv4[(size_t)j * 16 + cg];
      float4 z = zv4[(size_t)ic * 16 + cg];
      float4 h;
      h.x = fmaf(y.x + z.x + b1r[0], a1r[0], c1r[0]);
      h.y = fmaf(y.y + z.y + b1r[1], a1r[1], c1r[1]);
      h.z = fmaf(y.z + z.z + b1r[2], a1r[2], c1r[2]);
      h.w = fmaf(y.w + z.w + b1r[3], a1r[3], c1r[3]);
      h.x = h.x > 0.f ? h.x : 0.f; h.y = h.y > 0.f ? h.y : 0.f;
      h.z = h.z > 0.f ? h.z : 0.f; h.w = h.w > 0.f ? h.w : 0.f;
      *reinterpret_cast<float4*>(&h1s[el][o0]) = h;
      if (cg == 0) rowid[el] = valid ? r : -1;
    }
    __syncthreads();
    float acc[4][4];
#pragma unroll
    for (int r = 0; r < 4; ++r)
#pragma unroll
      for (int q = 0; q < 4; ++q) acc[r][q] = 0.f;
#pragma unroll 4
    for (int c4 = 0; c4 < 16; ++c4) {
      float4 h0 = *reinterpret_cast<const float4*>(&h1s[e0l + 0][c4 * 4]);
      float4 h1 = *reinterpret_cast<const float4*>(&h1s[e0l + 1][c4 * 4]);
      float4 h2 = *reinterpret_cast<const float4*>(&h1s[e0l + 2][c4 * 4]);
      float4 h3 = *reinterpret_cast<const float4*>(&h1s[e0l + 3][c4 * 4]);
      float4 w0 = *reinterpret_cast<const float4*>(&w2t[c4 * 4 + 0][o0]);
      float4 w1 = *reinterpret_cast<const float4*>(&w2t[c4 * 4 + 1][o0]);
      float4 w2 = *reinterpret_cast<const float4*>(&w2t[c4 * 4 + 2][o0]);
      float4 w3 = *reinterpret_cast<const float4*>(&w2t[c4 * 4 + 3][o0]);
#define GFMA(R, H)                                                       \
      acc[R][0] = fmaf(H.x, w0.x, acc[R][0]); acc[R][0] = fmaf(H.y, w1.x, acc[R][0]); \
      acc[R][0] = fmaf(H.z, w2.x, acc[R][0]); acc[R][0] = fmaf(H.w, w3.x, acc[R][0]); \
      acc[R][1] = fmaf(H.x, w0.y, acc[R][1]); acc[R][1] = fmaf(H.y, w1.y, acc[R][1]); \
      acc[R][1] = fmaf(H.z, w2.y, acc[R][1]); acc[R][1] = fmaf(H.w, w3.y, acc[R][1]); \
      acc[R][2] = fmaf(H.x, w0.z, acc[R][2]); acc[R][2] = fmaf(H.y, w1.z, acc[R][2]); \
      acc[R][2] = fmaf(H.z, w2.z, acc[R][2]); acc[R][2] = fmaf(H.w, w3.z, acc[R][2]); \
      acc[R][3] = fmaf(H.x, w0.w, acc[R][3]); acc[R][3] = fmaf(H.y, w1.w, acc[R][3]); \
      acc[R][3] = fmaf(H.z, w2.w, acc[R][3]); acc[R][3] = fmaf(H.w, w3.w, acc[R][3]);
      GFMA(0, h0) GFMA(1, h1) GFMA(2, h2) GFMA(3, h3)
#undef GFMA
    }
    int cur = -1;
    float mx[4], mn[4];
#pragma unroll
    for (int r = 0; r < 4; ++r) {
      int rw = rowid[e0l + r];
      float v[4];
#pragma unroll
      for (int q = 0; q < 4; ++q) v[q] = acc[r][q] + b2r[q];
      if (rw >= 0) {
#pragma unroll
        for (int q = 0; q < 4; ++q) { s1[q] += v[q]; s2[q] += v[q] * v[q]; }
      }
      if (rw != cur) {
        if (cur >= 0) {
#pragma unroll
          for (int q = 0; q < 4; ++q) {
            atomicMax(&maxt[cur][o0 + q], fmap(mx[q]));
            atomicMin(&mint[cur][o0 + q], fmap(mn[q]));
          }
        }
        cur = rw;
#pragma unroll
        for (int q = 0; q < 4; ++q) { mx[q] = v[q]; mn[q] = v[q]; }
      } else if (rw >= 0) {
#pragma unroll
        for (int q = 0; q < 4; ++q) {
          mx[q] = v[q] > mx[q] ? v[q] : mx[q];
          mn[q] = v[q] < mn[q] ? v[q] : mn[q];
        }
      }
    }
    if (cur >= 0) {
#pragma unroll
      for (int q = 0; q < 4; ++q) {
        atomicMax(&maxt[cur][o0 + q], fmap(mx[q]));
        atomicMin(&mint[cur][o0 + q], fmap(mn[q]));
      }
    }
  }
  __syncthreads();
  for (int m = t; m < 2048; m += 256) {
    int r = m >> 6, c = m & 63;
    mmax[(size_t)(r0 + r) * 64 + c] = maxt[r][c];
    mmin[(size_t)(r0 + r) * 64 + c] = mint[r][c];
  }
  if (t < 64) { ss[0][t] = 0.f; ss[1][t] = 0.f; }
  __syncthreads();
#pragma unroll
  for (int q = 0; q < 4; ++q) {
    s1[q] += __shfl_xor(s1[q], 16);
    s1[q] += __shfl_xor(s1[q], 32);
    s2[q] += __shfl_xor(s2[q], 16);
    s2[q] += __shfl_xor(s2[q], 32);
  }
  if ((t & 48) == 0) {
#pragma unroll
    for (int q = 0; q < 4; ++q) {
      atomicAdd(&ss[0][o0 + q], s1[q]);
      atomicAdd(&ss[1][o0 + q], s2[q]);
    }
  }
  __syncthreads();
  if (t < 64)       atomicAdd(&stats2[t], ss[0][t]);
  else if (t < 128) atomicAdd(&stats2[t - 64 + 64], ss[1][t - 64]);
}

// ---------------- finalize: BN2 affine of per-row max/min + relu + empties -
__global__ __launch_bounds__(256) void finalize_out(
    const float* __restrict__ stats2, const float* __restrict__ g2,
    const float* __restrict__ beta2, const int* __restrict__ cnt,
    const int* __restrict__ mmax, const int* __restrict__ mmin,
    const int* __restrict__ ovf_cnt, const int* __restrict__ ovf,
    const int* __restrict__ nbr, const float* __restrict__ yv,
    const float* __restrict__ zv, const float* __restrict__ b1,
    const float* __restrict__ stats1, const float* __restrict__ g1,
    const float* __restrict__ beta1, const float* __restrict__ W2,
    const float* __restrict__ b2, float* __restrict__ outp) {
  const int idx = blockIdx.x * 256 + threadIdx.x;
  const int row = idx >> 6, ch = idx & 63;
  constexpr float invE = 1.0f / NEDGE;
  float mu  = stats2[ch] * invE;
  float var = stats2[64 + ch] * invE - mu * mu;
  float a2  = g2[ch] * rsqrtf(var + 1e-5f);
  float c2  = beta2[ch] - mu * a2;
  float h = (a2 >= 0.f) ? funmap(mmax[idx]) : funmap(mmin[idx]);
  int ov = ovf_cnt[0]; ov = ov > OVCAP ? OVCAP : ov;
  for (int u = 0; u < ov; ++u) {
    int e = ovf[u];
    if (nbr[e] == row) {
      int ic = e / KNN_K;
      float accv = 0.f;
      for (int k = 0; k < 64; ++k) {
        float mu1  = stats1[k] * invE;
        float var1 = stats1[64 + k] * invE - mu1 * mu1;
        float a1   = g1[k] * rsqrtf(var1 + 1e-5f);
        float c1   = beta1[k] - mu1 * a1;
        float sI   = yv[(size_t)row * 64 + k] + zv[(size_t)ic * 64 + k] + b1[k];
        float hh   = fmaf(sI, a1, c1);
        hh = hh > 0.f ? hh : 0.f;
        accv = fmaf(hh, W2[ch * 64 + k], accv);
      }
      float v = accv + b2[ch];
      if (a2 >= 0.f) h = v > h ? v : h; else h = v < h ? v : h;
    }
  }
  float o = (cnt[row] > 0) ? fmaf(h, a2, c2) : 0.0f;
  outp[idx] = o > 0.f ? o : 0.f;
}

// --------------------------------------------------------------- launch ----
extern "C" void kernel_launch(void* const* d_in, const int* in_sizes, int n_in,
                              void* d_out, int out_size, void* d_ws, size_t ws_size,
                              hipStream_t stream) {
  (void)in_sizes; (void)n_in; (void)out_size;
  const float* x     = (const float*)d_in[0];
  const float* pos   = (const float*)d_in[1];
  const float* W1    = (const float*)d_in[3];
  const float* b1    = (const float*)d_in[4];
  const float* g1    = (const float*)d_in[5];
  const float* beta1 = (const float*)d_in[6];
  const float* W2    = (const float*)d_in[7];
  const float* b2    = (const float*)d_in[8];
  const float* g2    = (const float*)d_in[9];
  const float* beta2 = (const float*)d_in[10];
  float* outp = (float*)d_out;

  char* w = (char*)d_ws;
  int*   nbr     = (int*)w;                            // 1,310,720 B
  float* yv      = (float*)(w + 1310720);              // 4,194,304 B
  float* zv      = (float*)(w + 5505024);              // 4,194,304 B
  float* stats   = (float*)(w + 9699328);              // 1,024 B
  int*   cnt     = (int*)(w + 9700352);                // 65,536 B
  int*   ovf_cnt = (int*)(w + 9765888);                // 64 B
  int*   ovf     = (int*)(w + 9765952);                // 32,768 B
  int*   rev     = (int*)(w + 9798720);                // 8,388,608 B -> 18,187,328
  int*   mmax    = (int*)(w + 18187328);               // 4,194,304 B
  int*   mmin    = (int*)(w + 22381632);               // 4,194,304 B -> 26,575,936
  const size_t NEED_BIG = 26575936ull;
  const bool big = ws_size >= NEED_BIG;
  (void)big;

  hipMemsetAsync(stats, 0, 1024, stream);
  hipMemsetAsync(cnt, 0, 65536 + 64, stream);

  knn_kernel<<<NPT / 16, 256, 0, stream>>>(pos, nbr, cnt, ovf_cnt, ovf, rev);
  node_gemm<<<NPT / 4, 256, 0, stream>>>(x, W1, yv, zv);
  bn1_stats<<<NPT / 16, 256, 0, stream>>>(nbr, (const float4*)yv, (const float4*)zv, b1, stats);
  gemm2_seg<<<NPT / 32, 256, 0, stream>>>(
      (const float4*)yv, (const float4*)zv, b1, stats, g1, beta1, W2, b2,
      cnt, rev, stats + 128, mmax, mmin);
  finalize_out<<<NPT * 64 / 256, 256, 0, stream>>>(
      stats + 128, g2, beta2, cnt, mmax, mmin, ovf_cnt, ovf, nbr,
      yv, zv, b1, stats, g1, beta1, W2, b2, outp);
}

// Round 8
// 254.304 us; speedup vs baseline: 1.2775x; 1.1215x over previous
//
#include <hip/hip_runtime.h>

constexpr int BATCH = 8;
constexpr int PPC   = 2048;            // points per cloud
constexpr int NPT   = BATCH * PPC;     // 16384 points
constexpr int OCH   = 64;              // out channels (= in channels)
constexpr int KNN_K = 20;
constexpr int NEDGE = NPT * KNN_K;     // 327680 edges
constexpr int REVCAP = 128;            // per-row reverse-adjacency capacity
constexpr int OVCAP  = 8192;           // overflow list capacity
constexpr int QCAP   = 44;             // per-point qualifier capacity
constexpr int ROWS   = 16;             // rows per gemm2_seg block

typedef short short8 __attribute__((ext_vector_type(8)));
typedef float float4v __attribute__((ext_vector_type(4)));

__device__ __forceinline__ int fmap(float f) {   // monotone float->signed-int map
  int i = __float_as_int(f);
  return i >= 0 ? i : (i ^ 0x7FFFFFFF);
}
__device__ __forceinline__ float funmap(int m) {
  int i = m >= 0 ? m : (m ^ 0x7FFFFFFF);
  return __int_as_float(i);
}
__device__ __forceinline__ unsigned short bfr(float f) {  // f32 -> bf16 RNE
  unsigned u = __float_as_uint(f);
  return (unsigned short)((u + 0x7FFFu + ((u >> 16) & 1u)) >> 16);
}
__device__ __forceinline__ unsigned umed3(unsigned a, unsigned b, unsigned c) {
  unsigned d;
  asm("v_med3_u32 %0, %1, %2, %3" : "=v"(d) : "v"(a), "v"(b), "v"(c));
  return d;
}

// ---------------------------------------------------------------- kNN ------
// Block = 16 points x 16 splits (256 threads).
// P1: per-lane sorted top-20 DISTANCES via v_med3_u32 (1 op/slot).
// Merge: width-16 min-tournament with pop-all-ties -> global 20th value T.
// P2: push candidates with d2u<=T (~20/point) as u64 (d2,idx) into LDS.
// P3: exact rank by pairwise u64 compare (== jax top_k (d2,index) order).
__global__ __launch_bounds__(256) void knn_kernel(const float* __restrict__ pos,
                                                  int* __restrict__ nbr,
                                                  int* __restrict__ cnt,
                                                  int* __restrict__ ovf_cnt,
                                                  int* __restrict__ ovf,
                                                  int* __restrict__ rev) {
  __shared__ float4 cps[8 * 257];                 // region r at r*257 (+pad)
  __shared__ unsigned long long qk[16][QCAP];     // per-point qualifiers
  __shared__ int qn[16];
  const int t  = threadIdx.x;
  const int pl = t >> 4;                     // point-local 0..15
  const int s  = t & 15;                     // split 0..15
  const int lane = t & 63;
  const int i  = blockIdx.x * 16 + pl;
  const int cbase = i & ~(PPC - 1);

  for (int u = t; u < PPC; u += 256) {
    int j = cbase + u;
    float ax = pos[3 * j], ay = pos[3 * j + 1], az = pos[3 * j + 2];
    cps[(u >> 8) * 257 + (u & 255)] = make_float4(ax, ay, az, ax * ax + ay * ay + az * az);
  }
  if (t < 16) qn[t] = 0;
  __syncthreads();

  const int il = i - cbase;
  const float4 me = cps[(il >> 8) * 257 + (il & 255)];
  const float px = me.x, py = me.y, pz = me.z, sqi = me.w;
  const int jbase = s * 128;
  const float4* __restrict__ cp = &cps[(s >> 1) * 257 + (s & 1) * 128];

  unsigned kd[KNN_K];
#pragma unroll
  for (int q = 0; q < KNN_K; ++q) kd[q] = 0xFFFFFFFFu;
  for (int u = 0; u < 128; ++u) {
    float4 c = cp[u];
    float d2 = sqi + c.w - 2.0f * (px * c.x + py * c.y + pz * c.z);
    d2 = d2 > 0.f ? d2 : 0.f;
    unsigned ck = __float_as_uint(d2);
    ck = (jbase + u == il) ? 0xFFFFFFFFu : ck;
#pragma unroll
    for (int q = KNN_K - 1; q > 0; --q) kd[q] = umed3(kd[q - 1], kd[q], ck);
    kd[0] = kd[0] < ck ? kd[0] : ck;
  }

  unsigned T = 0xFFFFFFFFu;
  int cum = 0;
  const int grp = lane & 48;
#pragma unroll
  for (int r = 0; r < KNN_K; ++r) {
    unsigned w = kd[0];
#pragma unroll
    for (int m = 1; m < 16; m <<= 1) {
      unsigned o = (unsigned)__shfl_xor((int)w, m, 16);
      w = o < w ? o : w;
    }
    bool pop = (kd[0] == w);
    unsigned long long bal = __ballot(pop);
    int mcount = __popc((int)((bal >> grp) & 0xFFFFull));
    if (cum < KNN_K) T = w;
    cum += mcount;
    if (pop) {
#pragma unroll
      for (int q = 0; q < KNN_K - 1; ++q) kd[q] = kd[q + 1];
      kd[KNN_K - 1] = 0xFFFFFFFFu;
    }
  }

  for (int u = 0; u < 128; ++u) {
    float4 c = cp[u];
    float d2 = sqi + c.w - 2.0f * (px * c.x + py * c.y + pz * c.z);
    d2 = d2 > 0.f ? d2 : 0.f;
    unsigned ck = __float_as_uint(d2);
    ck = (jbase + u == il) ? 0xFFFFFFFFu : ck;
    if (ck <= T) {
      int slot = atomicAdd(&qn[pl], 1);
      if (slot < QCAP)
        qk[pl][slot] = ((unsigned long long)ck << 32) | (unsigned)(jbase + u);
    }
  }
  __syncthreads();

  int n = qn[pl]; n = n < QCAP ? n : QCAP;
  for (int base = 0; base < n; base += 16) {
    int e = base + s;
    if (e < n) {
      unsigned long long mk = qk[pl][e];
      int rank = 0;
      for (int o = 0; o < n; ++o) rank += (qk[pl][o] < mk) ? 1 : 0;
      if (rank < KNN_K) {
        int j = cbase + (int)(mk & 0xFFFFFFFFull);
        int eid = i * KNN_K + rank;
        nbr[eid] = j;
        int slot = atomicAdd(&cnt[j], 1);
        if (slot < REVCAP) rev[j * REVCAP + slot] = eid;
        else { int ov = atomicAdd(ovf_cnt, 1); if (ov < OVCAP) ovf[ov] = eid; }
      }
    }
  }
}

// ------------------------------------------------- node-level layer-1 GEMM -
__global__ __launch_bounds__(256) void node_gemm(const float* __restrict__ x,
                                                 const float* __restrict__ W1,
                                                 float* __restrict__ yv,
                                                 float* __restrict__ zv) {
  __shared__ float wa[64][65];
  __shared__ float wb[64][65];
  __shared__ float xs[4][64];
  const int t = threadIdx.x;
  for (int m = t; m < 8192; m += 256) {
    int o = m >> 7, c2 = m & 127;
    float w = W1[m];
    if (c2 < 64) wa[c2][o] = w; else wb[c2 - 64][o] = w;
  }
  const int nl = t >> 6, o = t & 63;
  xs[nl][o] = x[(size_t)(blockIdx.x * 4 + nl) * 64 + o];
  __syncthreads();
  float accA = 0.f, accB = 0.f;
#pragma unroll 8
  for (int c = 0; c < 64; ++c) {
    float xv = xs[nl][c];
    accA = fmaf(xv, wa[c][o], accA);
    accB = fmaf(xv, wb[c][o], accB);
  }
  size_t n = (size_t)blockIdx.x * 4 + nl;
  yv[n * 64 + o] = accA - accB;
  zv[n * 64 + o] = accB;
}

// ---------------------------- BN1 stats: center-grouped (z once, 20 y rows) -
__global__ __launch_bounds__(256) void bn1_stats(const int* __restrict__ nbr,
                                                 const float4* __restrict__ yv4,
                                                 const float4* __restrict__ zv4,
                                                 const float* __restrict__ b1,
                                                 float* __restrict__ stats) {
  const int t  = threadIdx.x;
  const int c4 = t & 15;
  const int lane = t & 63;
  const int i  = blockIdx.x * 16 + (t >> 4);
  const float4 bo = reinterpret_cast<const float4*>(b1)[c4];
  float4 z = zv4[(size_t)i * 16 + c4];
  float4 zb = make_float4(z.x + bo.x, z.y + bo.y, z.z + bo.z, z.w + bo.w);
  int jA = nbr[i * KNN_K + c4];
  int jB = nbr[i * KNN_K + 16 + (c4 & 3)];
  float4 s1 = make_float4(0, 0, 0, 0), s2 = make_float4(0, 0, 0, 0);
#pragma unroll
  for (int q = 0; q < 16; ++q) {
    int j = __shfl(jA, (lane & 48) + q);
    float4 y = yv4[(size_t)j * 16 + c4];
    float sx = y.x + zb.x, sy = y.y + zb.y, sz = y.z + zb.z, sw = y.w + zb.w;
    s1.x += sx; s1.y += sy; s1.z += sz; s1.w += sw;
    s2.x += sx * sx; s2.y += sy * sy; s2.z += sz * sz; s2.w += sw * sw;
  }
#pragma unroll
  for (int q = 0; q < 4; ++q) {
    int j = __shfl(jB, (lane & 48) + q);
    float4 y = yv4[(size_t)j * 16 + c4];
    float sx = y.x + zb.x, sy = y.y + zb.y, sz = y.z + zb.z, sw = y.w + zb.w;
    s1.x += sx; s1.y += sy; s1.z += sz; s1.w += sw;
    s2.x += sx * sx; s2.y += sy * sy; s2.z += sz * sz; s2.w += sw * sw;
  }
  s1.x += __shfl_xor(s1.x, 16); s1.y += __shfl_xor(s1.y, 16);
  s1.z += __shfl_xor(s1.z, 16); s1.w += __shfl_xor(s1.w, 16);
  s2.x += __shfl_xor(s2.x, 16); s2.y += __shfl_xor(s2.y, 16);
  s2.z += __shfl_xor(s2.z, 16); s2.w += __shfl_xor(s2.w, 16);
  s1.x += __shfl_xor(s1.x, 32); s1.y += __shfl_xor(s1.y, 32);
  s1.z += __shfl_xor(s1.z, 32); s1.w += __shfl_xor(s1.w, 32);
  s2.x += __shfl_xor(s2.x, 32); s2.y += __shfl_xor(s2.y, 32);
  s2.z += __shfl_xor(s2.z, 32); s2.w += __shfl_xor(s2.w, 32);
  __shared__ float ss[2][64];
  if (t < 128) { ss[0][t & 63] = 0.f; }
  __syncthreads();
  if ((t & 48) == 0) {
    atomicAdd(&ss[0][c4 * 4 + 0], s1.x); atomicAdd(&ss[0][c4 * 4 + 1], s1.y);
    atomicAdd(&ss[0][c4 * 4 + 2], s1.z); atomicAdd(&ss[0][c4 * 4 + 3], s1.w);
    atomicAdd(&ss[1][c4 * 4 + 0], s2.x); atomicAdd(&ss[1][c4 * 4 + 1], s2.y);
    atomicAdd(&ss[1][c4 * 4 + 2], s2.z); atomicAdd(&ss[1][c4 * 4 + 3], s2.w);
  }
  __syncthreads();
  if (t < 64)       atomicAdd(&stats[t], ss[0][t]);
  else if (t < 128) atomicAdd(&stats[64 + (t - 64)], ss[1][t - 64]);
}

// ------------- row-grouped GEMM2 (bf16 MFMA) + BN2 stats + per-row max/min -
// Block owns 16 rows. 64-edge tiles: stage h1 (BN1+relu) as bf16 row-major
// in LDS; W2 as bf16 row-major. mfma_f32_16x16x32_bf16:
//   A[m=lane&15][k=quad*8+j]  <- ds_read_b128 of h1b row
//   B[k=quad*8+j][n=lane&15]  <- ds_read_b128 of w2b row (W2[o][c] row-major)
//   D col=lane&15, row=quad*4+reg (HW-verified layout)
__global__ __launch_bounds__(256) void gemm2_seg(
    const float4* __restrict__ yv4, const float4* __restrict__ zv4,
    const float* __restrict__ b1, const float* __restrict__ stats1,
    const float* __restrict__ g1, const float* __restrict__ beta1,
    const float* __restrict__ W2, const float* __restrict__ b2,
    const int* __restrict__ cnt, const int* __restrict__ rev,
    float* __restrict__ stats2, int* __restrict__ mmax, int* __restrict__ mmin) {
  __shared__ unsigned short w2b[64][72];   // rows 144 B, 16-aligned
  __shared__ unsigned short h1b[64][72];
  __shared__ float a1s[64], c1s[64], b1s[64];
  __shared__ int   cct[ROWS];
  __shared__ int   offs[ROWS + 1];
  __shared__ int   rowid[64];
  __shared__ int   maxt[ROWS][64];
  __shared__ int   mint[ROWS][64];
  __shared__ float ss[2][64];
  const int t = threadIdx.x;
  const int r0 = blockIdx.x * ROWS;
  constexpr float invE = 1.0f / NEDGE;
  for (int m = t; m < 4096; m += 256) w2b[m >> 6][m & 63] = bfr(W2[m]);
  if (t < 64) {
    float mu  = stats1[t] * invE;
    float var = stats1[64 + t] * invE - mu * mu;
    float a   = g1[t] * rsqrtf(var + 1e-5f);
    a1s[t] = a; c1s[t] = beta1[t] - mu * a; b1s[t] = b1[t];
  }
  if (t < ROWS) { int c = cnt[r0 + t]; cct[t] = c < REVCAP ? c : REVCAP; }
  for (int m = t; m < ROWS * 64; m += 256) {
    (&maxt[0][0])[m] = 0x80000000;
    (&mint[0][0])[m] = 0x7FFFFFFF;
  }
  __syncthreads();
  if (t == 0) {
    int a = 0;
    for (int r = 0; r < ROWS; ++r) { offs[r] = a; a += cct[r]; }
    offs[ROWS] = a;
  }
  __syncthreads();
  const int total = offs[ROWS];
  const int eg = t >> 4, cg = t & 15;            // staging ids
  const int lane = t & 63, wv = t >> 6;          // mfma ids
  const int col = lane & 15, quad = lane >> 4;
  float a1r[4], c1r[4], b1r[4];
#pragma unroll
  for (int q = 0; q < 4; ++q) {
    a1r[q] = a1s[cg * 4 + q]; c1r[q] = c1s[cg * 4 + q]; b1r[q] = b1s[cg * 4 + q];
  }
  float b2r[4];
#pragma unroll
  for (int nt = 0; nt < 4; ++nt) b2r[nt] = b2[nt * 16 + col];
  float s1[4] = {0, 0, 0, 0}, s2[4] = {0, 0, 0, 0};
  const int ntiles = (total + 63) >> 6;
  for (int ti = 0; ti < ntiles; ++ti) {
    __syncthreads();
#pragma unroll
    for (int k = 0; k < 4; ++k) {
      int el = k * 16 + eg;
      int m  = ti * 64 + el;
      bool valid = m < total;
      int lo = 0, hi = ROWS;
#pragma unroll
      for (int st = 0; st < 4; ++st) {
        int mid = (lo + hi) >> 1;
        if (m >= offs[mid]) lo = mid; else hi = mid;
      }
      int r = lo;
      int e = valid ? rev[(size_t)(r0 + r) * REVCAP + (m - offs[r])] : 0;
      int j  = r0 + r;
      int ic = e / KNN_K;
      float4 y = yv4[(size_t)j * 16 + cg];
      float4 z = zv4[(size_t)ic * 16 + cg];
      float h0 = fmaf(y.x + z.x + b1r[0], a1r[0], c1r[0]);
      float h1 = fmaf(y.y + z.y + b1r[1], a1r[1], c1r[1]);
      float h2 = fmaf(y.z + z.z + b1r[2], a1r[2], c1r[2]);
      float h3 = fmaf(y.w + z.w + b1r[3], a1r[3], c1r[3]);
      h0 = h0 > 0.f ? h0 : 0.f; h1 = h1 > 0.f ? h1 : 0.f;
      h2 = h2 > 0.f ? h2 : 0.f; h3 = h3 > 0.f ? h3 : 0.f;
      uint2 p;
      p.x = (unsigned)bfr(h0) | ((unsigned)bfr(h1) << 16);
      p.y = (unsigned)bfr(h2) | ((unsigned)bfr(h3) << 16);
      *reinterpret_cast<uint2*>(&h1b[el][cg * 4]) = p;
      if (cg == 0) rowid[el] = valid ? r : -1;
    }
    __syncthreads();
    float4v acc[4];
#pragma unroll
    for (int nt = 0; nt < 4; ++nt) acc[nt] = (float4v){0.f, 0.f, 0.f, 0.f};
    short8 af0 = *reinterpret_cast<const short8*>(&h1b[wv * 16 + col][quad * 8]);
    short8 af1 = *reinterpret_cast<const short8*>(&h1b[wv * 16 + col][32 + quad * 8]);
#pragma unroll
    for (int nt = 0; nt < 4; ++nt) {
      short8 bf0 = *reinterpret_cast<const short8*>(&w2b[nt * 16 + col][quad * 8]);
      short8 bf1 = *reinterpret_cast<const short8*>(&w2b[nt * 16 + col][32 + quad * 8]);
      acc[nt] = __builtin_amdgcn_mfma_f32_16x16x32_bf16(af0, bf0, acc[nt], 0, 0, 0);
      acc[nt] = __builtin_amdgcn_mfma_f32_16x16x32_bf16(af1, bf1, acc[nt], 0, 0, 0);
    }
    // epilogue: D row = quad*4+r (edge), col/nt = channel
    const int eb = wv * 16 + quad * 4;
    int cur = -1;
    float mx[4], mn[4];
#pragma unroll
    for (int r = 0; r < 4; ++r) {
      int rw = rowid[eb + r];
      float v[4];
#pragma unroll
      for (int nt = 0; nt < 4; ++nt) v[nt] = acc[nt][r] + b2r[nt];
      if (rw >= 0) {
#pragma unroll
        for (int nt = 0; nt < 4; ++nt) { s1[nt] += v[nt]; s2[nt] += v[nt] * v[nt]; }
      }
      if (rw != cur) {
        if (cur >= 0) {
#pragma unroll
          for (int nt = 0; nt < 4; ++nt) {
            atomicMax(&maxt[cur][nt * 16 + col], fmap(mx[nt]));
            atomicMin(&mint[cur][nt * 16 + col], fmap(mn[nt]));
          }
        }
        cur = rw;
#pragma unroll
        for (int nt = 0; nt < 4; ++nt) { mx[nt] = v[nt]; mn[nt] = v[nt]; }
      } else if (rw >= 0) {
#pragma unroll
        for (int nt = 0; nt < 4; ++nt) {
          mx[nt] = v[nt] > mx[nt] ? v[nt] : mx[nt];
          mn[nt] = v[nt] < mn[nt] ? v[nt] : mn[nt];
        }
      }
    }
    if (cur >= 0) {
#pragma unroll
      for (int nt = 0; nt < 4; ++nt) {
        atomicMax(&maxt[cur][nt * 16 + col], fmap(mx[nt]));
        atomicMin(&mint[cur][nt * 16 + col], fmap(mn[nt]));
      }
    }
  }
  __syncthreads();
  for (int m = t; m < ROWS * 64; m += 256) {
    int r = m >> 6, c = m & 63;
    mmax[(size_t)(r0 + r) * 64 + c] = maxt[r][c];
    mmin[(size_t)(r0 + r) * 64 + c] = mint[r][c];
  }
  if (t < 64) { ss[0][t] = 0.f; ss[1][t] = 0.f; }
  __syncthreads();
#pragma unroll
  for (int nt = 0; nt < 4; ++nt) {
    s1[nt] += __shfl_xor(s1[nt], 16);
    s1[nt] += __shfl_xor(s1[nt], 32);
    s2[nt] += __shfl_xor(s2[nt], 16);
    s2[nt] += __shfl_xor(s2[nt], 32);
  }
  if ((t & 48) == 0) {
#pragma unroll
    for (int nt = 0; nt < 4; ++nt) {
      atomicAdd(&ss[0][nt * 16 + col], s1[nt]);
      atomicAdd(&ss[1][nt * 16 + col], s2[nt]);
    }
  }
  __syncthreads();
  if (t < 64)       atomicAdd(&stats2[t], ss[0][t]);
  else if (t < 128) atomicAdd(&stats2[t - 64 + 64], ss[1][t - 64]);
}

// ---------------- finalize: BN2 affine of per-row max/min + relu + empties -
__global__ __launch_bounds__(256) void finalize_out(
    const float* __restrict__ stats2, const float* __restrict__ g2,
    const float* __restrict__ beta2, const int* __restrict__ cnt,
    const int* __restrict__ mmax, const int* __restrict__ mmin,
    const int* __restrict__ ovf_cnt, const int* __restrict__ ovf,
    const int* __restrict__ nbr, const float* __restrict__ yv,
    const float* __restrict__ zv, const float* __restrict__ b1,
    const float* __restrict__ stats1, const float* __restrict__ g1,
    const float* __restrict__ beta1, const float* __restrict__ W2,
    const float* __restrict__ b2, float* __restrict__ outp) {
  const int idx = blockIdx.x * 256 + threadIdx.x;
  const int row = idx >> 6, ch = idx & 63;
  constexpr float invE = 1.0f / NEDGE;
  float mu  = stats2[ch] * invE;
  float var = stats2[64 + ch] * invE - mu * mu;
  float a2  = g2[ch] * rsqrtf(var + 1e-5f);
  float c2  = beta2[ch] - mu * a2;
  float h = (a2 >= 0.f) ? funmap(mmax[idx]) : funmap(mmin[idx]);
  int ov = ovf_cnt[0]; ov = ov > OVCAP ? OVCAP : ov;
  for (int u = 0; u < ov; ++u) {
    int e = ovf[u];
    if (nbr[e] == row) {
      int ic = e / KNN_K;
      float accv = 0.f;
      for (int k = 0; k < 64; ++k) {
        float mu1  = stats1[k] * invE;
        float var1 = stats1[64 + k] * invE - mu1 * mu1;
        float a1   = g1[k] * rsqrtf(var1 + 1e-5f);
        float c1   = beta1[k] - mu1 * a1;
        float sI   = yv[(size_t)row * 64 + k] + zv[(size_t)ic * 64 + k] + b1[k];
        float hh   = fmaf(sI, a1, c1);
        hh = hh > 0.f ? hh : 0.f;
        accv = fmaf(hh, W2[ch * 64 + k], accv);
      }
      float v = accv + b2[ch];
      if (a2 >= 0.f) h = v > h ? v : h; else h = v < h ? v : h;
    }
  }
  float o = (cnt[row] > 0) ? fmaf(h, a2, c2) : 0.0f;
  outp[idx] = o > 0.f ? o : 0.f;
}

// --------------------------------------------------------------- launch ----
extern "C" void kernel_launch(void* const* d_in, const int* in_sizes, int n_in,
                              void* d_out, int out_size, void* d_ws, size_t ws_size,
                              hipStream_t stream) {
  (void)in_sizes; (void)n_in; (void)out_size; (void)ws_size;
  const float* x     = (const float*)d_in[0];
  const float* pos   = (const float*)d_in[1];
  const float* W1    = (const float*)d_in[3];
  const float* b1    = (const float*)d_in[4];
  const float* g1    = (const float*)d_in[5];
  const float* beta1 = (const float*)d_in[6];
  const float* W2    = (const float*)d_in[7];
  const float* b2    = (const float*)d_in[8];
  const float* g2    = (const float*)d_in[9];
  const float* beta2 = (const float*)d_in[10];
  float* outp = (float*)d_out;

  char* w = (char*)d_ws;
  int*   nbr     = (int*)w;                            // 1,310,720 B
  float* yv      = (float*)(w + 1310720);              // 4,194,304 B
  float* zv      = (float*)(w + 5505024);              // 4,194,304 B
  float* stats   = (float*)(w + 9699328);              // 1,024 B
  int*   cnt     = (int*)(w + 9700352);                // 65,536 B
  int*   ovf_cnt = (int*)(w + 9765888);                // 64 B
  int*   ovf     = (int*)(w + 9765952);                // 32,768 B
  int*   rev     = (int*)(w + 9798720);                // 8,388,608 B -> 18,187,328
  int*   mmax    = (int*)(w + 18187328);               // 4,194,304 B
  int*   mmin    = (int*)(w + 22381632);               // 4,194,304 B -> 26,575,936

  hipMemsetAsync(stats, 0, 1024, stream);
  hipMemsetAsync(cnt, 0, 65536 + 64, stream);

  knn_kernel<<<NPT / 16, 256, 0, stream>>>(pos, nbr, cnt, ovf_cnt, ovf, rev);
  node_gemm<<<NPT / 4, 256, 0, stream>>>(x, W1, yv, zv);
  bn1_stats<<<NPT / 16, 256, 0, stream>>>(nbr, (const float4*)yv, (const float4*)zv, b1, stats);
  gemm2_seg<<<NPT / ROWS, 256, 0, stream>>>(
      (const float4*)yv, (const float4*)zv, b1, stats, g1, beta1, W2, b2,
      cnt, rev, stats + 128, mmax, mmin);
  finalize_out<<<NPT * 64 / 256, 256, 0, stream>>>(
      stats + 128, g2, beta2, cnt, mmax, mmin, ovf_cnt, ovf, nbr,
      yv, zv, b1, stats, g1, beta1, W2, b2, outp);
}

// Round 9
// 236.320 us; speedup vs baseline: 1.3748x; 1.0761x over previous
//
#include <hip/hip_runtime.h>

constexpr int BATCH = 8;
constexpr int PPC   = 2048;            // points per cloud
constexpr int NPT   = BATCH * PPC;     // 16384 points
constexpr int OCH   = 64;              // out channels (= in channels)
constexpr int KNN_K = 20;
constexpr int NEDGE = NPT * KNN_K;     // 327680 edges
constexpr int REVCAP = 128;            // per-row reverse-adjacency capacity
constexpr int OVCAP  = 8192;           // overflow list capacity
constexpr int QCAP   = 48;             // per-point qualifier capacity
constexpr int ROWS   = 16;             // rows per gemm2_seg block

typedef short short8 __attribute__((ext_vector_type(8)));
typedef float float4v __attribute__((ext_vector_type(4)));

__device__ __forceinline__ int fmap(float f) {   // monotone float->signed-int map
  int i = __float_as_int(f);
  return i >= 0 ? i : (i ^ 0x7FFFFFFF);
}
__device__ __forceinline__ float funmap(int m) {
  int i = m >= 0 ? m : (m ^ 0x7FFFFFFF);
  return __int_as_float(i);
}
__device__ __forceinline__ unsigned short bfr(float f) {  // f32 -> bf16 RNE
  unsigned u = __float_as_uint(f);
  return (unsigned short)((u + 0x7FFFu + ((u >> 16) & 1u)) >> 16);
}
__device__ __forceinline__ unsigned umed3(unsigned a, unsigned b, unsigned c) {
  unsigned d;
  asm("v_med3_u32 %0, %1, %2, %3" : "=v"(d) : "v"(a), "v"(b), "v"(c));
  return d;
}

// ---------------------------------------------------------------- kNN ------
// Block = 16 points x 16 splits (256 threads).
// P1: per-lane sorted top-3 DISTANCES (3 ops/cand). Any subset's 20th order
//     statistic >= the full set's, so the 20th smallest of the 48 per-lane
//     top-3 values is a valid upper bound T' >= true 20th distance.
// Merge: width-16 pop-tournament extracts that 20th-of-48 value T'.
// P2: push candidates with d2u<=T' (~25-30/point) as u64 (d2,idx) into LDS.
// P3: exact rank by pairwise u64 compare (== jax top_k (d2,index) order).
__global__ __launch_bounds__(256) void knn_kernel(const float* __restrict__ pos,
                                                  int* __restrict__ nbr,
                                                  int* __restrict__ cnt,
                                                  int* __restrict__ ovf_cnt,
                                                  int* __restrict__ ovf,
                                                  int* __restrict__ rev) {
  __shared__ float4 cps[8 * 257];                 // region r at r*257 (+pad)
  __shared__ unsigned long long qk[16][QCAP];     // per-point qualifiers
  __shared__ int qn[16];
  const int t  = threadIdx.x;
  const int pl = t >> 4;                     // point-local 0..15
  const int s  = t & 15;                     // split 0..15
  const int lane = t & 63;
  const int i  = blockIdx.x * 16 + pl;
  const int cbase = i & ~(PPC - 1);

  for (int u = t; u < PPC; u += 256) {
    int j = cbase + u;
    float ax = pos[3 * j], ay = pos[3 * j + 1], az = pos[3 * j + 2];
    cps[(u >> 8) * 257 + (u & 255)] = make_float4(ax, ay, az, ax * ax + ay * ay + az * az);
  }
  if (t < 16) qn[t] = 0;
  __syncthreads();

  const int il = i - cbase;
  const float4 me = cps[(il >> 8) * 257 + (il & 255)];
  const float px = me.x, py = me.y, pz = me.z, sqi = me.w;
  const int jbase = s * 128;
  const float4* __restrict__ cp = &cps[(s >> 1) * 257 + (s & 1) * 128];

  // ---- pass 1: per-lane top-3 distances (3 independent ops/candidate) ----
  unsigned kd[3];
  kd[0] = kd[1] = kd[2] = 0xFFFFFFFFu;
  for (int u = 0; u < 128; ++u) {
    float4 c = cp[u];
    float d2 = sqi + c.w - 2.0f * (px * c.x + py * c.y + pz * c.z);
    d2 = d2 > 0.f ? d2 : 0.f;
    unsigned ck = __float_as_uint(d2);
    ck = (jbase + u == il) ? 0xFFFFFFFFu : ck;
    kd[2] = umed3(kd[1], kd[2], ck);
    kd[1] = umed3(kd[0], kd[1], ck);
    kd[0] = kd[0] < ck ? kd[0] : ck;
  }

  // ---- merge: 20th smallest of the 48 head values -> threshold T' ----
  unsigned T = 0xFFFFFFFFu;
  int cum = 0;
  const int grp = lane & 48;
#pragma unroll
  for (int r = 0; r < KNN_K; ++r) {
    unsigned w = kd[0];
#pragma unroll
    for (int m = 1; m < 16; m <<= 1) {
      unsigned o = (unsigned)__shfl_xor((int)w, m, 16);
      w = o < w ? o : w;
    }
    bool pop = (kd[0] == w);
    unsigned long long bal = __ballot(pop);
    int mcount = __popc((int)((bal >> grp) & 0xFFFFull));
    if (cum < KNN_K) T = w;
    cum += mcount;
    if (pop) { kd[0] = kd[1]; kd[1] = kd[2]; kd[2] = 0xFFFFFFFFu; }
  }

  // ---- pass 2: push qualifiers (d2u <= T') ----
  for (int u = 0; u < 128; ++u) {
    float4 c = cp[u];
    float d2 = sqi + c.w - 2.0f * (px * c.x + py * c.y + pz * c.z);
    d2 = d2 > 0.f ? d2 : 0.f;
    unsigned ck = __float_as_uint(d2);
    ck = (jbase + u == il) ? 0xFFFFFFFFu : ck;
    if (ck <= T) {
      int slot = atomicAdd(&qn[pl], 1);
      if (slot < QCAP)
        qk[pl][slot] = ((unsigned long long)ck << 32) | (unsigned)(jbase + u);
    }
  }
  __syncthreads();

  // ---- pass 3: exact rank + emit nbr/rev ----
  int n = qn[pl]; n = n < QCAP ? n : QCAP;
  for (int base = 0; base < n; base += 16) {
    int e = base + s;
    if (e < n) {
      unsigned long long mk = qk[pl][e];
      int rank = 0;
      for (int o = 0; o < n; ++o) rank += (qk[pl][o] < mk) ? 1 : 0;
      if (rank < KNN_K) {
        int j = cbase + (int)(mk & 0xFFFFFFFFull);
        int eid = i * KNN_K + rank;
        nbr[eid] = j;
        int slot = atomicAdd(&cnt[j], 1);
        if (slot < REVCAP) rev[j * REVCAP + slot] = eid;
        else { int ov = atomicAdd(ovf_cnt, 1); if (ov < OVCAP) ovf[ov] = eid; }
      }
    }
  }
}

// ------------------------------------------------- node-level layer-1 GEMM -
__global__ __launch_bounds__(256) void node_gemm(const float* __restrict__ x,
                                                 const float* __restrict__ W1,
                                                 float* __restrict__ yv,
                                                 float* __restrict__ zv) {
  __shared__ float wa[64][65];
  __shared__ float wb[64][65];
  __shared__ float xs[4][64];
  const int t = threadIdx.x;
  for (int m = t; m < 8192; m += 256) {
    int o = m >> 7, c2 = m & 127;
    float w = W1[m];
    if (c2 < 64) wa[c2][o] = w; else wb[c2 - 64][o] = w;
  }
  const int nl = t >> 6, o = t & 63;
  xs[nl][o] = x[(size_t)(blockIdx.x * 4 + nl) * 64 + o];
  __syncthreads();
  float accA = 0.f, accB = 0.f;
#pragma unroll 8
  for (int c = 0; c < 64; ++c) {
    float xv = xs[nl][c];
    accA = fmaf(xv, wa[c][o], accA);
    accB = fmaf(xv, wb[c][o], accB);
  }
  size_t n = (size_t)blockIdx.x * 4 + nl;
  yv[n * 64 + o] = accA - accB;
  zv[n * 64 + o] = accB;
}

// ---------------------------- BN1 stats: center-grouped (z once, 20 y rows) -
__global__ __launch_bounds__(256) void bn1_stats(const int* __restrict__ nbr,
                                                 const float4* __restrict__ yv4,
                                                 const float4* __restrict__ zv4,
                                                 const float* __restrict__ b1,
                                                 float* __restrict__ stats) {
  const int t  = threadIdx.x;
  const int c4 = t & 15;
  const int lane = t & 63;
  const int i  = blockIdx.x * 16 + (t >> 4);
  const float4 bo = reinterpret_cast<const float4*>(b1)[c4];
  float4 z = zv4[(size_t)i * 16 + c4];
  float4 zb = make_float4(z.x + bo.x, z.y + bo.y, z.z + bo.z, z.w + bo.w);
  int jA = nbr[i * KNN_K + c4];
  int jB = nbr[i * KNN_K + 16 + (c4 & 3)];
  float4 s1 = make_float4(0, 0, 0, 0), s2 = make_float4(0, 0, 0, 0);
#pragma unroll
  for (int q = 0; q < 16; ++q) {
    int j = __shfl(jA, (lane & 48) + q);
    float4 y = yv4[(size_t)j * 16 + c4];
    float sx = y.x + zb.x, sy = y.y + zb.y, sz = y.z + zb.z, sw = y.w + zb.w;
    s1.x += sx; s1.y += sy; s1.z += sz; s1.w += sw;
    s2.x += sx * sx; s2.y += sy * sy; s2.z += sz * sz; s2.w += sw * sw;
  }
#pragma unroll
  for (int q = 0; q < 4; ++q) {
    int j = __shfl(jB, (lane & 48) + q);
    float4 y = yv4[(size_t)j * 16 + c4];
    float sx = y.x + zb.x, sy = y.y + zb.y, sz = y.z + zb.z, sw = y.w + zb.w;
    s1.x += sx; s1.y += sy; s1.z += sz; s1.w += sw;
    s2.x += sx * sx; s2.y += sy * sy; s2.z += sz * sz; s2.w += sw * sw;
  }
  s1.x += __shfl_xor(s1.x, 16); s1.y += __shfl_xor(s1.y, 16);
  s1.z += __shfl_xor(s1.z, 16); s1.w += __shfl_xor(s1.w, 16);
  s2.x += __shfl_xor(s2.x, 16); s2.y += __shfl_xor(s2.y, 16);
  s2.z += __shfl_xor(s2.z, 16); s2.w += __shfl_xor(s2.w, 16);
  s1.x += __shfl_xor(s1.x, 32); s1.y += __shfl_xor(s1.y, 32);
  s1.z += __shfl_xor(s1.z, 32); s1.w += __shfl_xor(s1.w, 32);
  s2.x += __shfl_xor(s2.x, 32); s2.y += __shfl_xor(s2.y, 32);
  s2.z += __shfl_xor(s2.z, 32); s2.w += __shfl_xor(s2.w, 32);
  __shared__ float ss[2][64];
  if (t < 128) { ss[0][t & 63] = 0.f; }
  __syncthreads();
  if ((t & 48) == 0) {
    atomicAdd(&ss[0][c4 * 4 + 0], s1.x); atomicAdd(&ss[0][c4 * 4 + 1], s1.y);
    atomicAdd(&ss[0][c4 * 4 + 2], s1.z); atomicAdd(&ss[0][c4 * 4 + 3], s1.w);
    atomicAdd(&ss[1][c4 * 4 + 0], s2.x); atomicAdd(&ss[1][c4 * 4 + 1], s2.y);
    atomicAdd(&ss[1][c4 * 4 + 2], s2.z); atomicAdd(&ss[1][c4 * 4 + 3], s2.w);
  }
  __syncthreads();
  if (t < 64)       atomicAdd(&stats[t], ss[0][t]);
  else if (t < 128) atomicAdd(&stats[64 + (t - 64)], ss[1][t - 64]);
}

// ------------- row-grouped GEMM2 (bf16 MFMA) + BN2 stats + per-row max/min -
__global__ __launch_bounds__(256) void gemm2_seg(
    const float4* __restrict__ yv4, const float4* __restrict__ zv4,
    const float* __restrict__ b1, const float* __restrict__ stats1,
    const float* __restrict__ g1, const float* __restrict__ beta1,
    const float* __restrict__ W2, const float* __restrict__ b2,
    const int* __restrict__ cnt, const int* __restrict__ rev,
    float* __restrict__ stats2, int* __restrict__ mmax, int* __restrict__ mmin) {
  __shared__ unsigned short w2b[64][72];   // rows 144 B, 16-aligned
  __shared__ unsigned short h1b[64][72];
  __shared__ float a1s[64], c1s[64], b1s[64];
  __shared__ int   cct[ROWS];
  __shared__ int   offs[ROWS + 1];
  __shared__ int   rowid[64];
  __shared__ int   maxt[ROWS][64];
  __shared__ int   mint[ROWS][64];
  __shared__ float ss[2][64];
  const int t = threadIdx.x;
  const int r0 = blockIdx.x * ROWS;
  constexpr float invE = 1.0f / NEDGE;
  for (int m = t; m < 4096; m += 256) w2b[m >> 6][m & 63] = bfr(W2[m]);
  if (t < 64) {
    float mu  = stats1[t] * invE;
    float var = stats1[64 + t] * invE - mu * mu;
    float a   = g1[t] * rsqrtf(var + 1e-5f);
    a1s[t] = a; c1s[t] = beta1[t] - mu * a; b1s[t] = b1[t];
  }
  if (t < ROWS) { int c = cnt[r0 + t]; cct[t] = c < REVCAP ? c : REVCAP; }
  for (int m = t; m < ROWS * 64; m += 256) {
    (&maxt[0][0])[m] = 0x80000000;
    (&mint[0][0])[m] = 0x7FFFFFFF;
  }
  __syncthreads();
  if (t == 0) {
    int a = 0;
    for (int r = 0; r < ROWS; ++r) { offs[r] = a; a += cct[r]; }
    offs[ROWS] = a;
  }
  __syncthreads();
  const int total = offs[ROWS];
  const int eg = t >> 4, cg = t & 15;            // staging ids
  const int lane = t & 63, wv = t >> 6;          // mfma ids
  const int col = lane & 15, quad = lane >> 4;
  float a1r[4], c1r[4], b1r[4];
#pragma unroll
  for (int q = 0; q < 4; ++q) {
    a1r[q] = a1s[cg * 4 + q]; c1r[q] = c1s[cg * 4 + q]; b1r[q] = b1s[cg * 4 + q];
  }
  float b2r[4];
#pragma unroll
  for (int nt = 0; nt < 4; ++nt) b2r[nt] = b2[nt * 16 + col];
  float s1[4] = {0, 0, 0, 0}, s2[4] = {0, 0, 0, 0};
  const int ntiles = (total + 63) >> 6;
  for (int ti = 0; ti < ntiles; ++ti) {
    __syncthreads();
#pragma unroll
    for (int k = 0; k < 4; ++k) {
      int el = k * 16 + eg;
      int m  = ti * 64 + el;
      bool valid = m < total;
      int lo = 0, hi = ROWS;
#pragma unroll
      for (int st = 0; st < 4; ++st) {
        int mid = (lo + hi) >> 1;
        if (m >= offs[mid]) lo = mid; else hi = mid;
      }
      int r = lo;
      int e = valid ? rev[(size_t)(r0 + r) * REVCAP + (m - offs[r])] : 0;
      int j  = r0 + r;
      int ic = e / KNN_K;
      float4 y = yv4[(size_t)j * 16 + cg];
      float4 z = zv4[(size_t)ic * 16 + cg];
      float h0 = fmaf(y.x + z.x + b1r[0], a1r[0], c1r[0]);
      float h1 = fmaf(y.y + z.y + b1r[1], a1r[1], c1r[1]);
      float h2 = fmaf(y.z + z.z + b1r[2], a1r[2], c1r[2]);
      float h3 = fmaf(y.w + z.w + b1r[3], a1r[3], c1r[3]);
      h0 = h0 > 0.f ? h0 : 0.f; h1 = h1 > 0.f ? h1 : 0.f;
      h2 = h2 > 0.f ? h2 : 0.f; h3 = h3 > 0.f ? h3 : 0.f;
      uint2 p;
      p.x = (unsigned)bfr(h0) | ((unsigned)bfr(h1) << 16);
      p.y = (unsigned)bfr(h2) | ((unsigned)bfr(h3) << 16);
      *reinterpret_cast<uint2*>(&h1b[el][cg * 4]) = p;
      if (cg == 0) rowid[el] = valid ? r : -1;
    }
    __syncthreads();
    float4v acc[4];
#pragma unroll
    for (int nt = 0; nt < 4; ++nt) acc[nt] = (float4v){0.f, 0.f, 0.f, 0.f};
    short8 af0 = *reinterpret_cast<const short8*>(&h1b[wv * 16 + col][quad * 8]);
    short8 af1 = *reinterpret_cast<const short8*>(&h1b[wv * 16 + col][32 + quad * 8]);
#pragma unroll
    for (int nt = 0; nt < 4; ++nt) {
      short8 bf0 = *reinterpret_cast<const short8*>(&w2b[nt * 16 + col][quad * 8]);
      short8 bf1 = *reinterpret_cast<const short8*>(&w2b[nt * 16 + col][32 + quad * 8]);
      acc[nt] = __builtin_amdgcn_mfma_f32_16x16x32_bf16(af0, bf0, acc[nt], 0, 0, 0);
      acc[nt] = __builtin_amdgcn_mfma_f32_16x16x32_bf16(af1, bf1, acc[nt], 0, 0, 0);
    }
    const int eb = wv * 16 + quad * 4;
    int cur = -1;
    float mx[4], mn[4];
#pragma unroll
    for (int r = 0; r < 4; ++r) {
      int rw = rowid[eb + r];
      float v[4];
#pragma unroll
      for (int nt = 0; nt < 4; ++nt) v[nt] = acc[nt][r] + b2r[nt];
      if (rw >= 0) {
#pragma unroll
        for (int nt = 0; nt < 4; ++nt) { s1[nt] += v[nt]; s2[nt] += v[nt] * v[nt]; }
      }
      if (rw != cur) {
        if (cur >= 0) {
#pragma unroll
          for (int nt = 0; nt < 4; ++nt) {
            atomicMax(&maxt[cur][nt * 16 + col], fmap(mx[nt]));
            atomicMin(&mint[cur][nt * 16 + col], fmap(mn[nt]));
          }
        }
        cur = rw;
#pragma unroll
        for (int nt = 0; nt < 4; ++nt) { mx[nt] = v[nt]; mn[nt] = v[nt]; }
      } else if (rw >= 0) {
#pragma unroll
        for (int nt = 0; nt < 4; ++nt) {
          mx[nt] = v[nt] > mx[nt] ? v[nt] : mx[nt];
          mn[nt] = v[nt] < mn[nt] ? v[nt] : mn[nt];
        }
      }
    }
    if (cur >= 0) {
#pragma unroll
      for (int nt = 0; nt < 4; ++nt) {
        atomicMax(&maxt[cur][nt * 16 + col], fmap(mx[nt]));
        atomicMin(&mint[cur][nt * 16 + col], fmap(mn[nt]));
      }
    }
  }
  __syncthreads();
  for (int m = t; m < ROWS * 64; m += 256) {
    int r = m >> 6, c = m & 63;
    mmax[(size_t)(r0 + r) * 64 + c] = maxt[r][c];
    mmin[(size_t)(r0 + r) * 64 + c] = mint[r][c];
  }
  if (t < 64) { ss[0][t] = 0.f; ss[1][t] = 0.f; }
  __syncthreads();
#pragma unroll
  for (int nt = 0; nt < 4; ++nt) {
    s1[nt] += __shfl_xor(s1[nt], 16);
    s1[nt] += __shfl_xor(s1[nt], 32);
    s2[nt] += __shfl_xor(s2[nt], 16);
    s2[nt] += __shfl_xor(s2[nt], 32);
  }
  if ((t & 48) == 0) {
#pragma unroll
    for (int nt = 0; nt < 4; ++nt) {
      atomicAdd(&ss[0][nt * 16 + col], s1[nt]);
      atomicAdd(&ss[1][nt * 16 + col], s2[nt]);
    }
  }
  __syncthreads();
  if (t < 64)       atomicAdd(&stats2[t], ss[0][t]);
  else if (t < 128) atomicAdd(&stats2[t - 64 + 64], ss[1][t - 64]);
}

// ---------------- finalize: BN2 affine of per-row max/min + relu + empties -
__global__ __launch_bounds__(256) void finalize_out(
    const float* __restrict__ stats2, const float* __restrict__ g2,
    const float* __restrict__ beta2, const int* __restrict__ cnt,
    const int* __restrict__ mmax, const int* __restrict__ mmin,
    const int* __restrict__ ovf_cnt, const int* __restrict__ ovf,
    const int* __restrict__ nbr, const float* __restrict__ yv,
    const float* __restrict__ zv, const float* __restrict__ b1,
    const float* __restrict__ stats1, const float* __restrict__ g1,
    const float* __restrict__ beta1, const float* __restrict__ W2,
    const float* __restrict__ b2, float* __restrict__ outp) {
  const int idx = blockIdx.x * 256 + threadIdx.x;
  const int row = idx >> 6, ch = idx & 63;
  constexpr float invE = 1.0f / NEDGE;
  float mu  = stats2[ch] * invE;
  float var = stats2[64 + ch] * invE - mu * mu;
  float a2  = g2[ch] * rsqrtf(var + 1e-5f);
  float c2  = beta2[ch] - mu * a2;
  float h = (a2 >= 0.f) ? funmap(mmax[idx]) : funmap(mmin[idx]);
  int ov = ovf_cnt[0]; ov = ov > OVCAP ? OVCAP : ov;
  for (int u = 0; u < ov; ++u) {
    int e = ovf[u];
    if (nbr[e] == row) {
      int ic = e / KNN_K;
      float accv = 0.f;
      for (int k = 0; k < 64; ++k) {
        float mu1  = stats1[k] * invE;
        float var1 = stats1[64 + k] * invE - mu1 * mu1;
        float a1   = g1[k] * rsqrtf(var1 + 1e-5f);
        float c1   = beta1[k] - mu1 * a1;
        float sI   = yv[(size_t)row * 64 + k] + zv[(size_t)ic * 64 + k] + b1[k];
        float hh   = fmaf(sI, a1, c1);
        hh = hh > 0.f ? hh : 0.f;
        accv = fmaf(hh, W2[ch * 64 + k], accv);
      }
      float v = accv + b2[ch];
      if (a2 >= 0.f) h = v > h ? v : h; else h = v < h ? v : h;
    }
  }
  float o = (cnt[row] > 0) ? fmaf(h, a2, c2) : 0.0f;
  outp[idx] = o > 0.f ? o : 0.f;
}

// --------------------------------------------------------------- launch ----
extern "C" void kernel_launch(void* const* d_in, const int* in_sizes, int n_in,
                              void* d_out, int out_size, void* d_ws, size_t ws_size,
                              hipStream_t stream) {
  (void)in_sizes; (void)n_in; (void)out_size; (void)ws_size;
  const float* x     = (const float*)d_in[0];
  const float* pos   = (const float*)d_in[1];
  const float* W1    = (const float*)d_in[3];
  const float* b1    = (const float*)d_in[4];
  const float* g1    = (const float*)d_in[5];
  const float* beta1 = (const float*)d_in[6];
  const float* W2    = (const float*)d_in[7];
  const float* b2    = (const float*)d_in[8];
  const float* g2    = (const float*)d_in[9];
  const float* beta2 = (const float*)d_in[10];
  float* outp = (float*)d_out;

  char* w = (char*)d_ws;
  int*   nbr     = (int*)w;                            // 1,310,720 B
  float* yv      = (float*)(w + 1310720);              // 4,194,304 B
  float* zv      = (float*)(w + 5505024);              // 4,194,304 B
  float* stats   = (float*)(w + 9699328);              // 1,024 B
  int*   cnt     = (int*)(w + 9700352);                // 65,536 B
  int*   ovf_cnt = (int*)(w + 9765888);                // 64 B
  int*   ovf     = (int*)(w + 9765952);                // 32,768 B
  int*   rev     = (int*)(w + 9798720);                // 8,388,608 B -> 18,187,328
  int*   mmax    = (int*)(w + 18187328);               // 4,194,304 B
  int*   mmin    = (int*)(w + 22381632);               // 4,194,304 B -> 26,575,936

  hipMemsetAsync(stats, 0, 1024, stream);
  hipMemsetAsync(cnt, 0, 65536 + 64, stream);

  knn_kernel<<<NPT / 16, 256, 0, stream>>>(pos, nbr, cnt, ovf_cnt, ovf, rev);
  node_gemm<<<NPT / 4, 256, 0, stream>>>(x, W1, yv, zv);
  bn1_stats<<<NPT / 16, 256, 0, stream>>>(nbr, (const float4*)yv, (const float4*)zv, b1, stats);
  gemm2_seg<<<NPT / ROWS, 256, 0, stream>>>(
      (const float4*)yv, (const float4*)zv, b1, stats, g1, beta1, W2, b2,
      cnt, rev, stats + 128, mmax, mmin);
  finalize_out<<<NPT * 64 / 256, 256, 0, stream>>>(
      stats + 128, g2, beta2, cnt, mmax, mmin, ovf_cnt, ovf, nbr,
      yv, zv, b1, stats, g1, beta1, W2, b2, outp);
}